// Round 1
// 525.732 us; speedup vs baseline: 1.0299x; 1.0299x over previous
//
#include <hip/hip_runtime.h>
#include <math.h>

#define N_C 100000
#define HD 128
#define SCAN_CHUNK 1024

typedef short v8s __attribute__((ext_vector_type(8)));
typedef float v4f __attribute__((ext_vector_type(4)));
typedef __attribute__((address_space(1))) const void gas_t;
typedef __attribute__((address_space(3))) void las_t;

__device__ __forceinline__ unsigned short f2bf(float f) {
  unsigned int u = __float_as_uint(f);
  u += 0x7fffu + ((u >> 16) & 1u);
  return (unsigned short)(u >> 16);
}

// exact relu on two packed bf16 halves (negative & -0 -> +0)
__device__ __forceinline__ unsigned int relu2(unsigned int u) {
  unsigned int m = ((u & 0x80008000u) >> 15) * 0xFFFFu;
  return u & ~m;
}

// ------------------------------------------------------------------
// fused prep kernels
// ------------------------------------------------------------------
__global__ void count3_kernel(const int* __restrict__ ei_s, int Es,
                              const int* __restrict__ ei_a, int Ea,
                              const int* __restrict__ ei_t, int Et,
                              int* __restrict__ cnt) {
  int e = blockIdx.x * 256 + threadIdx.x;
  int y = blockIdx.y;
  if (y == 0) {
    if (e < Es) atomicAdd(&cnt[ei_s[Es + e]], 1);
  } else if (y == 1) {
    if (e < Ea) atomicAdd(&cnt[N_C + ei_a[Ea + e]], 1);
  } else {
    if (e < Et) atomicAdd(&cnt[2 * N_C + ei_t[Et + e]], 1);
  }
}

__global__ void place3_kernel(const int* __restrict__ ei_s, int Es,
                              const int* __restrict__ ei_a, int Ea,
                              const int* __restrict__ ei_t, int Et,
                              const int* __restrict__ rs_all, int* __restrict__ fill,
                              int* __restrict__ src_s, int* __restrict__ src_a,
                              int* __restrict__ src_t, int n) {
  int e = blockIdx.x * 256 + threadIdx.x;
  int y = blockIdx.y;
  const int* ei; int E; const int* rs; int* fl; int* out;
  if (y == 0)      { ei = ei_s; E = Es; rs = rs_all;               fl = fill;         out = src_s; }
  else if (y == 1) { ei = ei_a; E = Ea; rs = rs_all + (n + 1);     fl = fill + n;     out = src_a; }
  else             { ei = ei_t; E = Et; rs = rs_all + 2 * (n + 1); fl = fill + 2 * n; out = src_t; }
  if (e < E) {
    int d = ei[E + e];
    int p = rs[d] + atomicAdd(&fl[d], 1);
    out[p] = ei[e];
  }
}

// ------------------------------------------------------------------
// 3-phase exclusive scan (batched over blockIdx.y); phaseA emits inv,
// phaseC zeroes cnt after reading (so place3 can reuse it as fill).
// ------------------------------------------------------------------
__global__ __launch_bounds__(256) void scan_phaseA(const int* __restrict__ cnt,
                                                   int* __restrict__ partial,
                                                   float* __restrict__ inv, int n) {
  __shared__ int sdata[256];
  const int y = blockIdx.y;
  const int* c = cnt + y * n;
  float* iv = inv + y * n;
  int base = blockIdx.x * SCAN_CHUNK + threadIdx.x * 4;
  int s = 0;
#pragma unroll
  for (int j = 0; j < 4; ++j) {
    int idx = base + j;
    if (idx < n) {
      int v = c[idx];
      s += v;
      iv[idx] = 1.0f / fmaxf((float)v, 1.0f);
    }
  }
  sdata[threadIdx.x] = s;
  __syncthreads();
  for (int off = 128; off > 0; off >>= 1) {
    if (threadIdx.x < off) sdata[threadIdx.x] += sdata[threadIdx.x + off];
    __syncthreads();
  }
  if (threadIdx.x == 0) partial[y * 128 + blockIdx.x] = sdata[0];
}

__global__ __launch_bounds__(256) void scan_phaseB(int* __restrict__ partial, int nb) {
  __shared__ int sdata[256];
  int* p = partial + blockIdx.y * 128;
  int t = threadIdx.x;
  int v = (t < nb) ? p[t] : 0;
  sdata[t] = v;
  __syncthreads();
  for (int off = 1; off < 256; off <<= 1) {
    int x = (t >= off) ? sdata[t - off] : 0;
    __syncthreads();
    sdata[t] += x;
    __syncthreads();
  }
  if (t < nb) p[t] = sdata[t] - v;
}

__global__ __launch_bounds__(256) void scan_phaseC(int* __restrict__ cnt,
                                                   const int* __restrict__ partial,
                                                   int* __restrict__ rs_all, int n) {
  __shared__ int sdata[256];
  const int y = blockIdx.y;
  int* c = cnt + y * n;
  int* rs = rs_all + y * (n + 1);
  int t = threadIdx.x;
  int base = blockIdx.x * SCAN_CHUNK + t * 4;
  int v[4];
  int s = 0;
#pragma unroll
  for (int j = 0; j < 4; ++j) {
    int idx = base + j;
    v[j] = (idx < n) ? c[idx] : 0;
    s += v[j];
    if (idx < n) c[idx] = 0;  // reuse as fill in place3
  }
  sdata[t] = s;
  __syncthreads();
  for (int off = 1; off < 256; off <<= 1) {
    int x = (t >= off) ? sdata[t - off] : 0;
    __syncthreads();
    sdata[t] += x;
    __syncthreads();
  }
  int run = sdata[t] - s + partial[y * 128 + blockIdx.x];
#pragma unroll
  for (int j = 0; j < 4; ++j) {
    int idx = base + j;
    if (idx < n) rs[idx] = run;
    run += v[j];
  }
}

__global__ void set_totals(int* rs_all, int Es, int Ea, int Et, int n) {
  if (threadIdx.x == 0) {
    rs_all[n] = Es;
    rs_all[(n + 1) + n] = Ea;
    rs_all[2 * (n + 1) + n] = Et;
  }
}

// ------------------------------------------------------------------
// single prep kernel: weight transposes+cvt (y=0..7), biases (y=8),
// packed head weight (y=9). grid (128, 10) x 256
// ------------------------------------------------------------------
__global__ void prep_weights(
    const float* __restrict__ c1s_Wl, const float* __restrict__ c1s_Wr,
    const float* __restrict__ c1a_Wr, const float* __restrict__ c1t_Wr,
    const float* __restrict__ c1a_Wl, const float* __restrict__ c1t_Wl,
    const float* __restrict__ c2s_Wl, const float* __restrict__ c2s_Wr,
    const float* __restrict__ c2a_Wr, const float* __restrict__ c2t_Wr,
    const float* __restrict__ c2a_Wl, const float* __restrict__ c2t_Wl,
    const float* __restrict__ c1s_bl, const float* __restrict__ c1a_bl,
    const float* __restrict__ c1t_bl, const float* __restrict__ c2s_bl,
    const float* __restrict__ c2a_bl, const float* __restrict__ c2t_bl,
    const float* __restrict__ Wt, const float* __restrict__ bt,
    const float* __restrict__ Wi, const float* __restrict__ bi,
    const float* __restrict__ Wm, const float* __restrict__ bm,
    unsigned short* __restrict__ Bt_c1s, unsigned short* __restrict__ Bt_W1s,
    unsigned short* __restrict__ Bt_c1a, unsigned short* __restrict__ Bt_c1t,
    unsigned short* __restrict__ Bt_c2s, unsigned short* __restrict__ Bt_W2s,
    unsigned short* __restrict__ Bt_c2a, unsigned short* __restrict__ Bt_c2t,
    unsigned short* __restrict__ Wht,
    float* __restrict__ b1s, float* __restrict__ b2s, float* __restrict__ bh) {
  int y = blockIdx.y;
  int idx = blockIdx.x * 256 + threadIdx.x;
  if (y == 8) {
    if (blockIdx.x == 0) {
      int t = threadIdx.x;
      if (t < 128) b1s[t] = c1s_bl[t] + c1a_bl[t] + c1t_bl[t];
      else b2s[t - 128] = c2s_bl[t - 128] + c2a_bl[t - 128] + c2t_bl[t - 128];
    } else if (blockIdx.x == 1) {
      int t = threadIdx.x;
      if (t < 16) {
        float v = 0.f;
        if (t < 5) v = bt[t];
        else if (t < 9) v = bi[t - 5];
        else if (t < 12) v = bm[t - 9];
        bh[t] = v;
      }
    }
    return;
  }
  if (y == 9) {
    if (idx < 16 * 128) {
      int o = idx >> 7, k = idx & 127;
      float v = 0.f;
      if (o < 5) v = Wt[k * 5 + o];
      else if (o < 9) v = Wi[k * 4 + (o - 5)];
      else if (o < 12) v = Wm[k * 3 + (o - 9)];
      Wht[o * 128 + k] = f2bf(v);
    }
    return;
  }
  int K = (y < 2) ? 256 : 128;
  if (idx >= K * 128) return;
  int k = idx >> 7, n = idx & 127;
  float v;
  unsigned short* out;
  switch (y) {
    case 0: v = c1s_Wl[idx]; out = Bt_c1s; break;
    case 1: v = c1s_Wr[idx] + c1a_Wr[idx] + c1t_Wr[idx]; out = Bt_W1s; break;
    case 2: v = c1a_Wl[idx]; out = Bt_c1a; break;
    case 3: v = c1t_Wl[idx]; out = Bt_c1t; break;
    case 4: v = c2s_Wl[idx]; out = Bt_c2s; break;
    case 5: v = c2s_Wr[idx] + c2a_Wr[idx] + c2t_Wr[idx]; out = Bt_W2s; break;
    case 6: v = c2a_Wl[idx]; out = Bt_c2a; break;
    default: v = c2t_Wl[idx]; out = Bt_c2t; break;
  }
  out[n * K + k] = f2bf(v);
}

// ------------------------------------------------------------------
// GEMM body, 2-phase double-buffered pipeline (T3/T4 minimum recipe):
//   C0(bf16) = A@B0 [, C1(bf16) = A@B1 + bias1]
// tile 128x128, 4 waves 2x2, BK=32, mfma 16x16x32 bf16.
// LDS per buffer: A 8KB + B0 8KB + B1 8KB, x2 buffers = 48KB (linear,
// XOR-swizzled addressing: slot s at row r holds col-group s^((r>>1)&3)
// -> 2-way bank aliasing max = free).
// bf16 operands staged via global_load_lds(16B); fp32 A reg-staged with
// issue-early / cvt+ds_write-late (overlaps MFMA phase).
// Raw s_barrier + explicit waitcnts keep prefetch in flight across the
// compute phase (no compiler-forced vmcnt(0) drain).
// A/C1 may alias (layer-2 in-place): block reads only its own 128 rows,
// all A reads drain before epilogue writes them.
// ------------------------------------------------------------------
template <int KD, bool DUAL, bool ABF16>
__device__ __forceinline__ void gemm_body(
    int bx, unsigned short* smem, const void* Av, int M,
    const unsigned short* __restrict__ B0t, const unsigned short* __restrict__ B1t,
    unsigned short* __restrict__ C0, unsigned short* C1,
    const float* __restrict__ bias1) {
  constexpr int NT = KD / 32;
  constexpr int BUF = 12288;  // shorts per buffer (3 x 4096)
  const int t = threadIdx.x;
  const int wave = t >> 6, lane = t & 63;
  const int wm = (wave & 1) * 64;
  const int wn = (wave >> 1) * 64;
  const int m0 = bx * 128;
  const int lrow = lane & 15, lq = lane >> 4;
  // swizzled fragment col offset (shorts): slot = lq ^ ((row>>1)&3); row base mult of 16
  const int fg = (lq ^ ((lrow >> 1) & 3)) * 8;
  // gload_lds staging lane constants: 1KB chunk = 16 rows x 64B
  const int sr = lane >> 2;                        // row within chunk
  const int sg = (lane & 3) ^ ((lane >> 3) & 3);   // swizzled source col-group

  const float* Af = (const float*)Av;
  const unsigned short* Ab = (const unsigned short*)Av;

  v4f acc0[4][4];
  v4f acc1[DUAL ? 4 : 1][DUAL ? 4 : 1];
#pragma unroll
  for (int i = 0; i < 4; ++i)
#pragma unroll
    for (int j = 0; j < 4; ++j) acc0[i][j] = (v4f)(0.f);
  if constexpr (DUAL) {
#pragma unroll
    for (int i = 0; i < 4; ++i)
#pragma unroll
      for (int j = 0; j < 4; ++j) acc1[i][j] = (v4f)(0.f);
  }

  float4 ar[4];  // fp32-A staging registers (16 VGPR)

  auto stageB = [&](const unsigned short* __restrict__ Bt, unsigned short* lds, int k0) {
#pragma unroll
    for (int j = 0; j < 2; ++j) {
      int cidx = j * 4 + wave;
      const unsigned short* src = Bt + (size_t)(cidx * 16 + sr) * KD + k0 + sg * 8;
      __builtin_amdgcn_global_load_lds((gas_t*)src, (las_t*)(lds + cidx * 512), 16, 0, 0);
    }
  };
  auto stageAb = [&](unsigned short* lds, int k0) {
#pragma unroll
    for (int j = 0; j < 2; ++j) {
      int cidx = j * 4 + wave;
      int gr = m0 + cidx * 16 + sr;
      if (gr >= M) gr = M - 1;  // clamp: OOB rows read garbage, never written back
      const unsigned short* src = Ab + (size_t)gr * KD + k0 + sg * 8;
      __builtin_amdgcn_global_load_lds((gas_t*)src, (las_t*)(lds + cidx * 512), 16, 0, 0);
    }
  };
  auto loadAf = [&](int k0) {
    int r = t >> 1, h = t & 1;
    int gr = m0 + r;
    if (gr < M) {
      const float* src = Af + (size_t)gr * KD + k0 + h * 16;
#pragma unroll
      for (int j = 0; j < 4; ++j) ar[j] = *(const float4*)(src + j * 4);
    } else {
#pragma unroll
      for (int j = 0; j < 4; ++j) ar[j] = make_float4(0.f, 0.f, 0.f, 0.f);
    }
  };
  auto writeAf = [&](unsigned short* lds) {
    int r = t >> 1, h = t & 1;
    int sw = (r >> 1) & 3;
    auto pk = [](float a, float b) {
      return (unsigned int)f2bf(a) | ((unsigned int)f2bf(b) << 16);
    };
    uint4 w0 = make_uint4(pk(ar[0].x, ar[0].y), pk(ar[0].z, ar[0].w),
                          pk(ar[1].x, ar[1].y), pk(ar[1].z, ar[1].w));
    uint4 w1 = make_uint4(pk(ar[2].x, ar[2].y), pk(ar[2].z, ar[2].w),
                          pk(ar[3].x, ar[3].y), pk(ar[3].z, ar[3].w));
    *(uint4*)&lds[r * 32 + ((2 * h) ^ sw) * 8] = w0;
    *(uint4*)&lds[r * 32 + ((2 * h + 1) ^ sw) * 8] = w1;
  };
  auto stage = [&](int buf, int k0) {
    unsigned short* base = smem + buf * BUF;
    if constexpr (ABF16) stageAb(base, k0);
    else loadAf(k0);  // issue A reg-loads first (oldest in vmcnt queue)
    stageB(B0t, base + 4096, k0);
    if constexpr (DUAL) stageB(B1t, base + 8192, k0);
  };

  // ---- prologue: stage tile 0 into buffer 0, full drain, barrier ----
  stage(0, 0);
  if constexpr (!ABF16) writeAf(smem);  // compiler auto-waits the A regs
  asm volatile("s_waitcnt vmcnt(0)" ::: "memory");
  asm volatile("s_waitcnt lgkmcnt(0)" ::: "memory");
  asm volatile("s_barrier" ::: "memory");

#pragma unroll
  for (int kt = 0; kt < NT; ++kt) {
    unsigned short* cb_ = smem + (kt & 1) * BUF;
    const int nb = (kt & 1) ^ 1;
    // issue prefetch of tile kt+1 (flight overlaps this tile's MFMAs)
    if (kt + 1 < NT) stage(nb, (kt + 1) * 32);

    unsigned short* cAs = cb_;
    unsigned short* cB0 = cb_ + 4096;
    unsigned short* cB1 = cb_ + 8192;
    v8s af[4];
#pragma unroll
    for (int mt = 0; mt < 4; ++mt)
      af[mt] = *(const v8s*)&cAs[(wm + mt * 16 + lrow) * 32 + fg];
#pragma unroll
    for (int cbi = 0; cbi < 4; ++cbi) {
      v8s b0 = *(const v8s*)&cB0[(wn + cbi * 16 + lrow) * 32 + fg];
#pragma unroll
      for (int mt = 0; mt < 4; ++mt)
        acc0[mt][cbi] = __builtin_amdgcn_mfma_f32_16x16x32_bf16(af[mt], b0, acc0[mt][cbi], 0, 0, 0);
      if constexpr (DUAL) {
        v8s b1 = *(const v8s*)&cB1[(wn + cbi * 16 + lrow) * 32 + fg];
#pragma unroll
        for (int mt = 0; mt < 4; ++mt)
          acc1[mt][cbi] = __builtin_amdgcn_mfma_f32_16x16x32_bf16(af[mt], b1, acc1[mt][cbi], 0, 0, 0);
      }
    }
    if (kt + 1 < NT) {
      if constexpr (!ABF16) writeAf(smem + nb * BUF);  // cvt+write late (T14)
      asm volatile("s_waitcnt vmcnt(0)" ::: "memory");
      asm volatile("s_waitcnt lgkmcnt(0)" ::: "memory");
      asm volatile("s_barrier" ::: "memory");
    }
  }

  // ---- epilogue ----
  float bv[4] = {0.f, 0.f, 0.f, 0.f};
  if constexpr (DUAL) {
#pragma unroll
    for (int cbi = 0; cbi < 4; ++cbi) bv[cbi] = bias1[wn + cbi * 16 + lrow];
  }
#pragma unroll
  for (int mt = 0; mt < 4; ++mt) {
#pragma unroll
    for (int r = 0; r < 4; ++r) {
      int gr = m0 + wm + mt * 16 + lq * 4 + r;
      if (gr < M) {
#pragma unroll
        for (int cbi = 0; cbi < 4; ++cbi) {
          int gc = wn + cbi * 16 + lrow;
          C0[(size_t)gr * 128 + gc] = f2bf(acc0[mt][cbi][r]);
          if constexpr (DUAL) C1[(size_t)gr * 128 + gc] = f2bf(acc1[mt][cbi][r] + bv[cbi]);
        }
      }
    }
  }
}

// ------------------------------------------------------------------
// fused per-layer GEMM dispatchers (segment switch on blockIdx.x)
// dynamic LDS = 2 buffers * 3 tiles * 4096 shorts = 49152 bytes
// ------------------------------------------------------------------
__global__ __launch_bounds__(256, 2) void layer1_kernel(
    const float* __restrict__ xc, int Mc,
    const unsigned short* __restrict__ Bc0, const unsigned short* __restrict__ Bc1,
    unsigned short* __restrict__ y_s, unsigned short* __restrict__ h1,
    const float* __restrict__ b1s,
    const float* __restrict__ xt, int Mt, const unsigned short* __restrict__ Bt_,
    unsigned short* __restrict__ y_a,
    const float* __restrict__ xcl, int Mcl, const unsigned short* __restrict__ Bcl,
    unsigned short* __restrict__ y_t, int nbC, int nbT) {
  extern __shared__ unsigned short smem[];
  int b = blockIdx.x;
  if (b < nbC)
    gemm_body<256, true, false>(b, smem, xc, Mc, Bc0, Bc1, y_s, h1, b1s);
  else if (b < nbC + nbT)
    gemm_body<128, false, false>(b - nbC, smem, xt, Mt, Bt_, nullptr, y_a, nullptr, nullptr);
  else
    gemm_body<128, false, false>(b - nbC - nbT, smem, xcl, Mcl, Bcl, nullptr, y_t, nullptr, nullptr);
}

__global__ __launch_bounds__(256, 2) void layer2_kernel(
    unsigned short* h1, int Mc,
    const unsigned short* __restrict__ Bc0, const unsigned short* __restrict__ Bc1,
    unsigned short* __restrict__ y_s, const float* __restrict__ b2s,
    const float* __restrict__ xt, int Mt, const unsigned short* __restrict__ Bt_,
    unsigned short* __restrict__ y_a,
    const float* __restrict__ xcl, int Mcl, const unsigned short* __restrict__ Bcl,
    unsigned short* __restrict__ y_t, int nbC, int nbT) {
  extern __shared__ unsigned short smem[];
  int b = blockIdx.x;
  if (b < nbC)
    gemm_body<128, true, true>(b, smem, h1, Mc, Bc0, Bc1, y_s, h1, b2s);  // h1 already relu'd
  else if (b < nbC + nbT)
    gemm_body<128, false, false>(b - nbC, smem, xt, Mt, Bt_, nullptr, y_a, nullptr, nullptr);
  else
    gemm_body<128, false, false>(b - nbC - nbT, smem, xcl, Mcl, Bcl, nullptr, y_t, nullptr, nullptr);
}

// ------------------------------------------------------------------
// fused CSR gather, quarter-wave per edge; h is bf16 (RMW by quarter 0)
// final write applies relu (h = relu(self + aggregates)) so downstream
// GEMM/heads stages consume bf16 directly via global_load_lds.
// ------------------------------------------------------------------
__global__ __launch_bounds__(256) void gather_kernel(
    const unsigned short* __restrict__ ys, const unsigned short* __restrict__ ya,
    const unsigned short* __restrict__ yt,
    const int* __restrict__ rs_all,
    const int* __restrict__ src_s, const int* __restrict__ src_a,
    const int* __restrict__ src_t,
    const float* __restrict__ inv, unsigned short* h, int M) {
  int row = blockIdx.x * 4 + (threadIdx.x >> 6);
  if (row >= M) return;
  const int lane = threadIdx.x & 63;
  const int q = lane >> 4;
  const int col = (lane & 15) * 8;
  const int NP = M + 1;

  int b0 = rs_all[row],          e0 = rs_all[row + 1];
  int b1 = rs_all[NP + row],     e1 = rs_all[NP + row + 1];
  int b2 = rs_all[2 * NP + row], e2 = rs_all[2 * NP + row + 1];
  float sc0 = inv[row], sc1 = inv[M + row], sc2 = inv[2 * M + row];

  float acc[8];
#pragma unroll
  for (int j = 0; j < 8; ++j) acc[j] = 0.f;

  auto seg = [&](const unsigned short* __restrict__ y, const int* __restrict__ src,
                 int b, int e, float sc) {
    float s[8];
#pragma unroll
    for (int j = 0; j < 8; ++j) s[j] = 0.f;
    for (int i = b + q; i < e; i += 4) {
      int si = src[i];
      uint4 v = *(const uint4*)(y + (size_t)si * HD + col);
      s[0] += __uint_as_float(v.x << 16);
      s[1] += __uint_as_float(v.x & 0xffff0000u);
      s[2] += __uint_as_float(v.y << 16);
      s[3] += __uint_as_float(v.y & 0xffff0000u);
      s[4] += __uint_as_float(v.z << 16);
      s[5] += __uint_as_float(v.z & 0xffff0000u);
      s[6] += __uint_as_float(v.w << 16);
      s[7] += __uint_as_float(v.w & 0xffff0000u);
    }
#pragma unroll
    for (int j = 0; j < 8; ++j) acc[j] += s[j] * sc;
  };
  seg(ys, src_s, b0, e0, sc0);
  seg(ya, src_a, b1, e1, sc1);
  seg(yt, src_t, b2, e2, sc2);

#pragma unroll
  for (int j = 0; j < 8; ++j) {
    acc[j] += __shfl_xor(acc[j], 16);
    acc[j] += __shfl_xor(acc[j], 32);
  }
  if (q == 0) {
    uint4 hv = *(uint4*)(h + (size_t)row * HD + col);
    auto upd = [&](unsigned int u, float a0, float a1) {
      float lo = fmaxf(__uint_as_float(u << 16) + a0, 0.f);
      float hi = fmaxf(__uint_as_float(u & 0xffff0000u) + a1, 0.f);
      return (unsigned int)f2bf(lo) | ((unsigned int)f2bf(hi) << 16);
    };
    hv.x = upd(hv.x, acc[0], acc[1]);
    hv.y = upd(hv.y, acc[2], acc[3]);
    hv.z = upd(hv.z, acc[4], acc[5]);
    hv.w = upd(hv.w, acc[6], acc[7]);
    *(uint4*)(h + (size_t)row * HD + col) = hv;
  }
}

// ------------------------------------------------------------------
// fused heads: P = relu(h2)@Wht^T + bh (MFMA) -> LDS -> epilogue
// 64 rows/block, 4 waves; thread t<64 does row t's sigmoid/softmax/impl
// (h2 is already relu'd by gather; relu2 here is an idempotent no-op)
// ------------------------------------------------------------------
__global__ __launch_bounds__(256, 4) void heads_kernel(
    const unsigned short* __restrict__ h2b, int M,
    const unsigned short* __restrict__ Wht, const float* __restrict__ bh,
    const float* __restrict__ Wm,
    float* __restrict__ out_t, float* __restrict__ out_i,
    float* __restrict__ out_m) {
  constexpr int AST_H = 136;
  __shared__ unsigned short As[64 * AST_H];
  __shared__ float Ps[64][17];
  const int t = threadIdx.x;
  const int wave = t >> 6, lane = t & 63;
  const int m0 = blockIdx.x * 64;
  const int lrow = lane & 15, lq = lane >> 4;

#pragma unroll
  for (int j = 0; j < 4; ++j) {
    int idx = j * 256 + t;
    int row = idx >> 4;
    int c8 = idx & 15;
    int gr = m0 + row;
    uint4 v = make_uint4(0, 0, 0, 0);
    if (gr < M) v = *(const uint4*)(h2b + (size_t)gr * 128 + c8 * 8);
    v.x = relu2(v.x); v.y = relu2(v.y); v.z = relu2(v.z); v.w = relu2(v.w);
    *(uint4*)&As[row * AST_H + c8 * 8] = v;
  }
  __syncthreads();

  v4f acc = (v4f)(0.f);
#pragma unroll
  for (int ks = 0; ks < 4; ++ks) {
    v8s a = *(const v8s*)&As[(wave * 16 + lrow) * AST_H + ks * 32 + lq * 8];
    v8s b = *(const v8s*)(Wht + lrow * 128 + ks * 32 + lq * 8);
    acc = __builtin_amdgcn_mfma_f32_16x16x32_bf16(a, b, acc, 0, 0, 0);
  }
  float bv = bh[lrow];
#pragma unroll
  for (int r = 0; r < 4; ++r)
    Ps[wave * 16 + lq * 4 + r][lrow] = acc[r] + bv;
  __syncthreads();

  if (t < 64) {
    int row = m0 + t;
    if (row < M) {
      float t_[5], i_[4], mb[3];
#pragma unroll
      for (int o = 0; o < 5; ++o) t_[o] = Ps[t][o];
#pragma unroll
      for (int o = 0; o < 4; ++o) i_[o] = Ps[t][5 + o];
#pragma unroll
      for (int o = 0; o < 3; ++o) mb[o] = Ps[t][9 + o];
      float tp[5];
#pragma unroll
      for (int o = 0; o < 5; ++o) tp[o] = 1.f / (1.f + __expf(-t_[o]));
      float mx = fmaxf(fmaxf(i_[0], i_[1]), fmaxf(i_[2], i_[3]));
      float ex[4], es = 0.f;
#pragma unroll
      for (int o = 0; o < 4; ++o) { ex[o] = __expf(i_[o] - mx); es += ex[o]; }
      float inv_es = 1.f / es;
      float ml[3];
#pragma unroll
      for (int o = 0; o < 3; ++o) {
        float v = mb[o];
#pragma unroll
        for (int j = 0; j < 5; ++j) v += tp[j] * Wm[(128 + j) * 3 + o];
#pragma unroll
        for (int j = 0; j < 4; ++j) v += (ex[j] * inv_es) * Wm[(133 + j) * 3 + o];
        ml[o] = v;
      }
#pragma unroll
      for (int o = 0; o < 5; ++o) out_t[(size_t)row * 5 + o] = t_[o];
#pragma unroll
      for (int o = 0; o < 4; ++o) out_i[(size_t)row * 4 + o] = i_[o];
#pragma unroll
      for (int o = 0; o < 3; ++o) out_m[(size_t)row * 3 + o] = ml[o];
    }
  }
}

// ------------------------------------------------------------------
extern "C" void kernel_launch(void* const* d_in, const int* in_sizes, int n_in,
                              void* d_out, int out_size, void* d_ws, size_t ws_size,
                              hipStream_t stream) {
  const float* x_comment = (const float*)d_in[0];
  const float* x_topic   = (const float*)d_in[1];
  const float* x_claim   = (const float*)d_in[2];
  const float* c1s_Wl = (const float*)d_in[3];
  const float* c1s_bl = (const float*)d_in[4];
  const float* c1s_Wr = (const float*)d_in[5];
  const float* c1a_Wl = (const float*)d_in[6];
  const float* c1a_bl = (const float*)d_in[7];
  const float* c1a_Wr = (const float*)d_in[8];
  const float* c1t_Wl = (const float*)d_in[9];
  const float* c1t_bl = (const float*)d_in[10];
  const float* c1t_Wr = (const float*)d_in[11];
  const float* c2s_Wl = (const float*)d_in[12];
  const float* c2s_bl = (const float*)d_in[13];
  const float* c2s_Wr = (const float*)d_in[14];
  const float* c2a_Wl = (const float*)d_in[15];
  const float* c2a_bl = (const float*)d_in[16];
  const float* c2a_Wr = (const float*)d_in[17];
  const float* c2t_Wl = (const float*)d_in[18];
  const float* c2t_bl = (const float*)d_in[19];
  const float* c2t_Wr = (const float*)d_in[20];
  const float* Wt = (const float*)d_in[21];
  const float* bt = (const float*)d_in[22];
  const float* Wi = (const float*)d_in[23];
  const float* bi = (const float*)d_in[24];
  const float* Wm = (const float*)d_in[25];
  const float* bm = (const float*)d_in[26];
  const int* ei_sim = (const int*)d_in[27];
  const int* ei_ab  = (const int*)d_in[28];
  const int* ei_tg  = (const int*)d_in[29];

  const int E_sim = in_sizes[27] / 2;
  const int E_ab  = in_sizes[28] / 2;
  const int E_tg  = in_sizes[29] / 2;
  const int N_T = in_sizes[1] / 128;
  const int N_CL = in_sizes[2] / 128;

  float* ws = (float*)d_ws;
  unsigned short* h1 = (unsigned short*)ws;                // 100000*128 bf16
  unsigned short* y_s = (unsigned short*)(ws + 12800000);  // 100000*128 bf16
  unsigned short* y_a = (unsigned short*)(ws + 19200000);  // 5000*128 bf16
  unsigned short* y_t = (unsigned short*)(ws + 19520000);  // 20000*128 bf16
  int*   cnt    = (int*)(ws + 20800000);                   // 3*N_C
  float* inv    = ws + 21100000;                           // 3*N_C
  int*   rs_all = (int*)(ws + 21400000);                   // 3*(N_C+1)
  int*   src_s  = (int*)(ws + 21700016);                   // E_sim
  int*   src_a  = (int*)(ws + 22300016);                   // E_ab
  int*   src_t  = (int*)(ws + 22600016);                   // E_tg
  int*   part   = (int*)(ws + 22900016);                   // 3*128
  float* b1s    = ws + 22900416;
  float* b2s    = ws + 22900544;
  unsigned short* Bt_c1s = (unsigned short*)(ws + 22900672);  // 128x256
  unsigned short* Bt_W1s = Bt_c1s + 32768;                    // 128x256
  unsigned short* Bt_c1a = Bt_W1s + 32768;                    // 128x128
  unsigned short* Bt_c1t = Bt_c1a + 16384;
  unsigned short* Bt_c2s = Bt_c1t + 16384;
  unsigned short* Bt_W2s = Bt_c2s + 16384;
  unsigned short* Bt_c2a = Bt_W2s + 16384;
  unsigned short* Bt_c2t = Bt_c2a + 16384;
  unsigned short* Wht = (unsigned short*)(ws + 24600000);     // 16x128 bf16
  float* bh     = ws + 24601100;                              // 16

  const int nbS = (N_C + SCAN_CHUNK - 1) / SCAN_CHUNK;
  const int ebx = (E_sim + 255) / 256;
  const int nbC = (N_C + 127) / 128;
  const int nbT = (N_T + 127) / 128;
  const int nbCl = (N_CL + 127) / 128;
  const size_t lds_bytes = 2 * 12288 * sizeof(unsigned short);  // 49152

  // ---- weight prep ----
  prep_weights<<<dim3(128, 10), 256, 0, stream>>>(
      c1s_Wl, c1s_Wr, c1a_Wr, c1t_Wr, c1a_Wl, c1t_Wl,
      c2s_Wl, c2s_Wr, c2a_Wr, c2t_Wr, c2a_Wl, c2t_Wl,
      c1s_bl, c1a_bl, c1t_bl, c2s_bl, c2a_bl, c2t_bl,
      Wt, bt, Wi, bi, Wm, bm,
      Bt_c1s, Bt_W1s, Bt_c1a, Bt_c1t, Bt_c2s, Bt_W2s, Bt_c2a, Bt_c2t,
      Wht, b1s, b2s, bh);

  // ---- degree histogram + CSR build ----
  hipMemsetAsync(cnt, 0, 3 * N_C * sizeof(int), stream);
  count3_kernel<<<dim3(ebx, 3), 256, 0, stream>>>(ei_sim, E_sim, ei_ab, E_ab, ei_tg, E_tg, cnt);
  scan_phaseA<<<dim3(nbS, 3), 256, 0, stream>>>(cnt, part, inv, N_C);
  scan_phaseB<<<dim3(1, 3), 256, 0, stream>>>(part, nbS);
  scan_phaseC<<<dim3(nbS, 3), 256, 0, stream>>>(cnt, part, rs_all, N_C);
  set_totals<<<1, 64, 0, stream>>>(rs_all, E_sim, E_ab, E_tg, N_C);
  place3_kernel<<<dim3(ebx, 3), 256, 0, stream>>>(
      ei_sim, E_sim, ei_ab, E_ab, ei_tg, E_tg, rs_all, cnt, src_s, src_a, src_t, N_C);

  // ---------------- layer 1 (fused 3 GEMMs) ----------------
  layer1_kernel<<<nbC + nbT + nbCl, 256, lds_bytes, stream>>>(
      x_comment, N_C, Bt_c1s, Bt_W1s, y_s, h1, b1s,
      x_topic, N_T, Bt_c1a, y_a,
      x_claim, N_CL, Bt_c1t, y_t, nbC, nbT);

  gather_kernel<<<(N_C + 3) / 4, 256, 0, stream>>>(
      y_s, y_a, y_t, rs_all, src_s, src_a, src_t, inv, h1, N_C);

  // ---------------- layer 2 (fused 3 GEMMs, h in-place bf16) --------
  layer2_kernel<<<nbC + nbT + nbCl, 256, lds_bytes, stream>>>(
      h1, N_C, Bt_c2s, Bt_W2s, y_s, b2s,
      x_topic, N_T, Bt_c2a, y_a,
      x_claim, N_CL, Bt_c2t, y_t, nbC, nbT);

  gather_kernel<<<(N_C + 3) / 4, 256, 0, stream>>>(
      y_s, y_a, y_t, rs_all, src_s, src_a, src_t, inv, h1, N_C);

  // ---------------- heads (fully fused) ----------------
  float* out = (float*)d_out;
  heads_kernel<<<(N_C + 63) / 64, 256, 0, stream>>>(
      h1, N_C, Wht, bh, Wm,
      out, out + (size_t)N_C * 5, out + (size_t)N_C * 9);
}

// Round 2
// 524.045 us; speedup vs baseline: 1.0332x; 1.0032x over previous
//
#include <hip/hip_runtime.h>
#include <math.h>

#define N_C 100000
#define HD 128
#define SCAN_CHUNK 1024

typedef short v8s __attribute__((ext_vector_type(8)));
typedef float v4f __attribute__((ext_vector_type(4)));
typedef __attribute__((address_space(1))) const void gas_t;
typedef __attribute__((address_space(3))) void las_t;

__device__ __forceinline__ unsigned short f2bf(float f) {
  unsigned int u = __float_as_uint(f);
  u += 0x7fffu + ((u >> 16) & 1u);
  return (unsigned short)(u >> 16);
}

// exact relu on two packed bf16 halves (negative & -0 -> +0)
__device__ __forceinline__ unsigned int relu2(unsigned int u) {
  unsigned int m = ((u & 0x80008000u) >> 15) * 0xFFFFu;
  return u & ~m;
}

// counted-wait helpers (immediates must be literals)
__device__ __forceinline__ void s_vmcnt0() { asm volatile("s_waitcnt vmcnt(0)" ::: "memory"); }
__device__ __forceinline__ void s_vmcnt2() { asm volatile("s_waitcnt vmcnt(2)" ::: "memory"); }
__device__ __forceinline__ void s_vmcnt4() { asm volatile("s_waitcnt vmcnt(4)" ::: "memory"); }
__device__ __forceinline__ void s_vmcnt8() { asm volatile("s_waitcnt vmcnt(8)" ::: "memory"); }
__device__ __forceinline__ void s_lgkm0() { asm volatile("s_waitcnt lgkmcnt(0)" ::: "memory"); }
__device__ __forceinline__ void s_bar() { __builtin_amdgcn_s_barrier(); }

// ------------------------------------------------------------------
// fused prep kernels
// ------------------------------------------------------------------
__global__ void count3_kernel(const int* __restrict__ ei_s, int Es,
                              const int* __restrict__ ei_a, int Ea,
                              const int* __restrict__ ei_t, int Et,
                              int* __restrict__ cnt) {
  int e = blockIdx.x * 256 + threadIdx.x;
  int y = blockIdx.y;
  if (y == 0) {
    if (e < Es) atomicAdd(&cnt[ei_s[Es + e]], 1);
  } else if (y == 1) {
    if (e < Ea) atomicAdd(&cnt[N_C + ei_a[Ea + e]], 1);
  } else {
    if (e < Et) atomicAdd(&cnt[2 * N_C + ei_t[Et + e]], 1);
  }
}

__global__ void place3_kernel(const int* __restrict__ ei_s, int Es,
                              const int* __restrict__ ei_a, int Ea,
                              const int* __restrict__ ei_t, int Et,
                              const int* __restrict__ rs_all, int* __restrict__ fill,
                              int* __restrict__ src_s, int* __restrict__ src_a,
                              int* __restrict__ src_t, int n) {
  int e = blockIdx.x * 256 + threadIdx.x;
  int y = blockIdx.y;
  const int* ei; int E; const int* rs; int* fl; int* out;
  if (y == 0)      { ei = ei_s; E = Es; rs = rs_all;               fl = fill;         out = src_s; }
  else if (y == 1) { ei = ei_a; E = Ea; rs = rs_all + (n + 1);     fl = fill + n;     out = src_a; }
  else             { ei = ei_t; E = Et; rs = rs_all + 2 * (n + 1); fl = fill + 2 * n; out = src_t; }
  if (e < E) {
    int d = ei[E + e];
    int p = rs[d] + atomicAdd(&fl[d], 1);
    out[p] = ei[e];
  }
}

// ------------------------------------------------------------------
// 3-phase exclusive scan (batched over blockIdx.y); phaseA emits inv,
// phaseC zeroes cnt after reading (so place3 can reuse it as fill).
// ------------------------------------------------------------------
__global__ __launch_bounds__(256) void scan_phaseA(const int* __restrict__ cnt,
                                                   int* __restrict__ partial,
                                                   float* __restrict__ inv, int n) {
  __shared__ int sdata[256];
  const int y = blockIdx.y;
  const int* c = cnt + y * n;
  float* iv = inv + y * n;
  int base = blockIdx.x * SCAN_CHUNK + threadIdx.x * 4;
  int s = 0;
#pragma unroll
  for (int j = 0; j < 4; ++j) {
    int idx = base + j;
    if (idx < n) {
      int v = c[idx];
      s += v;
      iv[idx] = 1.0f / fmaxf((float)v, 1.0f);
    }
  }
  sdata[threadIdx.x] = s;
  __syncthreads();
  for (int off = 128; off > 0; off >>= 1) {
    if (threadIdx.x < off) sdata[threadIdx.x] += sdata[threadIdx.x + off];
    __syncthreads();
  }
  if (threadIdx.x == 0) partial[y * 128 + blockIdx.x] = sdata[0];
}

__global__ __launch_bounds__(256) void scan_phaseB(int* __restrict__ partial, int nb) {
  __shared__ int sdata[256];
  int* p = partial + blockIdx.y * 128;
  int t = threadIdx.x;
  int v = (t < nb) ? p[t] : 0;
  sdata[t] = v;
  __syncthreads();
  for (int off = 1; off < 256; off <<= 1) {
    int x = (t >= off) ? sdata[t - off] : 0;
    __syncthreads();
    sdata[t] += x;
    __syncthreads();
  }
  if (t < nb) p[t] = sdata[t] - v;
}

__global__ __launch_bounds__(256) void scan_phaseC(int* __restrict__ cnt,
                                                   const int* __restrict__ partial,
                                                   int* __restrict__ rs_all, int n) {
  __shared__ int sdata[256];
  const int y = blockIdx.y;
  int* c = cnt + y * n;
  int* rs = rs_all + y * (n + 1);
  int t = threadIdx.x;
  int base = blockIdx.x * SCAN_CHUNK + t * 4;
  int v[4];
  int s = 0;
#pragma unroll
  for (int j = 0; j < 4; ++j) {
    int idx = base + j;
    v[j] = (idx < n) ? c[idx] : 0;
    s += v[j];
    if (idx < n) c[idx] = 0;  // reuse as fill in place3
  }
  sdata[t] = s;
  __syncthreads();
  for (int off = 1; off < 256; off <<= 1) {
    int x = (t >= off) ? sdata[t - off] : 0;
    __syncthreads();
    sdata[t] += x;
    __syncthreads();
  }
  int run = sdata[t] - s + partial[y * 128 + blockIdx.x];
#pragma unroll
  for (int j = 0; j < 4; ++j) {
    int idx = base + j;
    if (idx < n) rs[idx] = run;
    run += v[j];
  }
}

__global__ void set_totals(int* rs_all, int Es, int Ea, int Et, int n) {
  if (threadIdx.x == 0) {
    rs_all[n] = Es;
    rs_all[(n + 1) + n] = Ea;
    rs_all[2 * (n + 1) + n] = Et;
  }
}

// ------------------------------------------------------------------
// single prep kernel: weight transposes+cvt (y=0..7), biases (y=8),
// packed head weight (y=9). grid (128, 10) x 256
// ------------------------------------------------------------------
__global__ void prep_weights(
    const float* __restrict__ c1s_Wl, const float* __restrict__ c1s_Wr,
    const float* __restrict__ c1a_Wr, const float* __restrict__ c1t_Wr,
    const float* __restrict__ c1a_Wl, const float* __restrict__ c1t_Wl,
    const float* __restrict__ c2s_Wl, const float* __restrict__ c2s_Wr,
    const float* __restrict__ c2a_Wr, const float* __restrict__ c2t_Wr,
    const float* __restrict__ c2a_Wl, const float* __restrict__ c2t_Wl,
    const float* __restrict__ c1s_bl, const float* __restrict__ c1a_bl,
    const float* __restrict__ c1t_bl, const float* __restrict__ c2s_bl,
    const float* __restrict__ c2a_bl, const float* __restrict__ c2t_bl,
    const float* __restrict__ Wt, const float* __restrict__ bt,
    const float* __restrict__ Wi, const float* __restrict__ bi,
    const float* __restrict__ Wm, const float* __restrict__ bm,
    unsigned short* __restrict__ Bt_c1s, unsigned short* __restrict__ Bt_W1s,
    unsigned short* __restrict__ Bt_c1a, unsigned short* __restrict__ Bt_c1t,
    unsigned short* __restrict__ Bt_c2s, unsigned short* __restrict__ Bt_W2s,
    unsigned short* __restrict__ Bt_c2a, unsigned short* __restrict__ Bt_c2t,
    unsigned short* __restrict__ Wht,
    float* __restrict__ b1s, float* __restrict__ b2s, float* __restrict__ bh) {
  int y = blockIdx.y;
  int idx = blockIdx.x * 256 + threadIdx.x;
  if (y == 8) {
    if (blockIdx.x == 0) {
      int t = threadIdx.x;
      if (t < 128) b1s[t] = c1s_bl[t] + c1a_bl[t] + c1t_bl[t];
      else b2s[t - 128] = c2s_bl[t - 128] + c2a_bl[t - 128] + c2t_bl[t - 128];
    } else if (blockIdx.x == 1) {
      int t = threadIdx.x;
      if (t < 16) {
        float v = 0.f;
        if (t < 5) v = bt[t];
        else if (t < 9) v = bi[t - 5];
        else if (t < 12) v = bm[t - 9];
        bh[t] = v;
      }
    }
    return;
  }
  if (y == 9) {
    if (idx < 16 * 128) {
      int o = idx >> 7, k = idx & 127;
      float v = 0.f;
      if (o < 5) v = Wt[k * 5 + o];
      else if (o < 9) v = Wi[k * 4 + (o - 5)];
      else if (o < 12) v = Wm[k * 3 + (o - 9)];
      Wht[o * 128 + k] = f2bf(v);
    }
    return;
  }
  int K = (y < 2) ? 256 : 128;
  if (idx >= K * 128) return;
  int k = idx >> 7, n = idx & 127;
  float v;
  unsigned short* out;
  switch (y) {
    case 0: v = c1s_Wl[idx]; out = Bt_c1s; break;
    case 1: v = c1s_Wr[idx] + c1a_Wr[idx] + c1t_Wr[idx]; out = Bt_W1s; break;
    case 2: v = c1a_Wl[idx]; out = Bt_c1a; break;
    case 3: v = c1t_Wl[idx]; out = Bt_c1t; break;
    case 4: v = c2s_Wl[idx]; out = Bt_c2s; break;
    case 5: v = c2s_Wr[idx] + c2a_Wr[idx] + c2t_Wr[idx]; out = Bt_W2s; break;
    case 6: v = c2a_Wl[idx]; out = Bt_c2a; break;
    default: v = c2t_Wl[idx]; out = Bt_c2t; break;
  }
  out[n * K + k] = f2bf(v);
}

// ------------------------------------------------------------------
// GEMM body, depth-2 counted-vmcnt pipeline (T3+T4):
//   C0(bf16) = A@B0 [, C1(bf16) = A@B1 + bias1]
// tile 128x128, 4 waves 2x2, BK=32, mfma 16x16x32 bf16.
// LDS (exactly 64KB): A double-buffer 2x8KB + B triple-buffer 3x16KB
// (B0+B1 per buffer; single-B kernels leave B1 half unused).
// B tiles issued 2 K-steps ahead via global_load_lds; A one step ahead
// (bf16: gload_lds; fp32: reg-load early + cvt/ds_write late).
// One s_barrier per K-step; counted vmcnt waits (4/2), vmcnt(0) only at
// the final step -> prefetch stays in flight across barriers.
// Wait-count derivation (in-order vmem retirement, per wave):
//   iter kt: [wait Wtop][barrier][issue A(kt+1), B(kt+2)][ds_read+MFMA]
//            [fp32: wait Wmid; ds_write A(kt+1); lgkmcnt(0)]
//   Wtop leaves the younger tiles' loads (B = 4 dual / 2 single) in
//   flight; Wmid retires through the A reg-loads. Verified for all
//   instantiations incl. prologue (A0,B0,B1 pre-issued) and tail.
// A/C1 may alias (layer-2 in-place): block reads only its own 128 rows,
// all loads drained (final vmcnt(0)) before epilogue stores.
// ------------------------------------------------------------------
template <int KD, bool DUAL, bool ABF16>
__device__ __forceinline__ void gemm_body(
    int bx, unsigned short* smem, const void* Av, int M,
    const unsigned short* __restrict__ B0t, const unsigned short* __restrict__ B1t,
    unsigned short* __restrict__ C0, unsigned short* C1,
    const float* __restrict__ bias1) {
  constexpr int NT = KD / 32;
  const int t = threadIdx.x;
  const int wave = t >> 6, lane = t & 63;
  const int wm = (wave & 1) * 64;
  const int wn = (wave >> 1) * 64;
  const int m0 = bx * 128;
  const int lrow = lane & 15, lq = lane >> 4;
  // swizzled fragment col offset (shorts): slot = lq ^ ((row>>1)&3)
  const int fg = (lq ^ ((lrow >> 1) & 3)) * 8;
  // gload_lds staging lane constants: 1KB chunk = 16 rows x 64B
  const int sr = lane >> 2;                        // row within chunk
  const int sg = (lane & 3) ^ ((lane >> 3) & 3);   // swizzled source col-group

  const float* Af = (const float*)Av;
  const unsigned short* Ab_g = (const unsigned short*)Av;

  auto Abuf = [&](int i) { return smem + (i & 1) * 4096; };
  auto Bbuf = [&](int i) { return smem + 8192 + (i % 3) * 8192; };

  v4f acc0[4][4];
  v4f acc1[DUAL ? 4 : 1][DUAL ? 4 : 1];
#pragma unroll
  for (int i = 0; i < 4; ++i)
#pragma unroll
    for (int j = 0; j < 4; ++j) acc0[i][j] = (v4f)(0.f);
  if constexpr (DUAL) {
#pragma unroll
    for (int i = 0; i < 4; ++i)
#pragma unroll
      for (int j = 0; j < 4; ++j) acc1[i][j] = (v4f)(0.f);
  }

  float4 ar[4];  // fp32-A staging registers (16 VGPR)

  auto stageB1 = [&](const unsigned short* __restrict__ Bt, unsigned short* lds, int k0) {
#pragma unroll
    for (int j = 0; j < 2; ++j) {
      int cidx = j * 4 + wave;
      const unsigned short* src = Bt + (size_t)(cidx * 16 + sr) * KD + k0 + sg * 8;
      __builtin_amdgcn_global_load_lds((gas_t*)src, (las_t*)(lds + cidx * 512), 16, 0, 0);
    }
  };
  auto stageB2 = [&](unsigned short* ldsB, int k0) {
    stageB1(B0t, ldsB, k0);
    if constexpr (DUAL) stageB1(B1t, ldsB + 4096, k0);
  };
  auto stageAb = [&](unsigned short* lds, int k0) {
#pragma unroll
    for (int j = 0; j < 2; ++j) {
      int cidx = j * 4 + wave;
      int gr = m0 + cidx * 16 + sr;
      if (gr >= M) gr = M - 1;  // clamp: OOB rows read garbage, never written back
      const unsigned short* src = Ab_g + (size_t)gr * KD + k0 + sg * 8;
      __builtin_amdgcn_global_load_lds((gas_t*)src, (las_t*)(lds + cidx * 512), 16, 0, 0);
    }
  };
  auto loadAf = [&](int k0) {
    int r = t >> 1, h = t & 1;
    int gr = m0 + r;
    if (gr < M) {
      const float* src = Af + (size_t)gr * KD + k0 + h * 16;
#pragma unroll
      for (int j = 0; j < 4; ++j) ar[j] = *(const float4*)(src + j * 4);
    } else {
#pragma unroll
      for (int j = 0; j < 4; ++j) ar[j] = make_float4(0.f, 0.f, 0.f, 0.f);
    }
  };
  auto writeAf = [&](unsigned short* lds) {
    int r = t >> 1, h = t & 1;
    int sw = (r >> 1) & 3;
    auto pk = [](float a, float b) {
      return (unsigned int)f2bf(a) | ((unsigned int)f2bf(b) << 16);
    };
    uint4 w0 = make_uint4(pk(ar[0].x, ar[0].y), pk(ar[0].z, ar[0].w),
                          pk(ar[1].x, ar[1].y), pk(ar[1].z, ar[1].w));
    uint4 w1 = make_uint4(pk(ar[2].x, ar[2].y), pk(ar[2].z, ar[2].w),
                          pk(ar[3].x, ar[3].y), pk(ar[3].z, ar[3].w));
    *(uint4*)&lds[r * 32 + ((2 * h) ^ sw) * 8] = w0;
    *(uint4*)&lds[r * 32 + ((2 * h + 1) ^ sw) * 8] = w1;
  };

  // ---- prologue: A(0) + B(0),B(1) in flight ----
  if constexpr (ABF16) {
    stageAb(Abuf(0), 0);
  } else {
    loadAf(0);
  }
  stageB2(Bbuf(0), 0);
  if (1 < NT) stageB2(Bbuf(1), 32);
  if constexpr (!ABF16) {
    if constexpr (DUAL) s_vmcnt8(); else s_vmcnt4();  // A regs landed
    writeAf(Abuf(0));
    s_lgkm0();  // A(0) visible before the iter-0 barrier
  }

#pragma unroll
  for (int kt = 0; kt < NT; ++kt) {
    // top wait: own tile-kt loads retired; younger tiles stay in flight
    if (kt == NT - 1) { s_vmcnt0(); }
    else { if constexpr (DUAL) s_vmcnt4(); else s_vmcnt2(); }
    s_bar();  // joins: tile kt fully in LDS; all waves done reading old bufs

    // issue next tiles (A: +1, B: +2) -- after barrier (WAR-safe)
    if (kt + 1 < NT) {
      if constexpr (ABF16) stageAb(Abuf(kt + 1), (kt + 1) * 32);
      else loadAf((kt + 1) * 32);
    }
    if (kt + 2 < NT) stageB2(Bbuf(kt + 2), (kt + 2) * 32);

    unsigned short* cAs = Abuf(kt);
    unsigned short* cB0 = Bbuf(kt);
    unsigned short* cB1 = cB0 + 4096;
    v8s af[4];
#pragma unroll
    for (int mt = 0; mt < 4; ++mt)
      af[mt] = *(const v8s*)&cAs[(wm + mt * 16 + lrow) * 32 + fg];
    __builtin_amdgcn_s_setprio(1);
#pragma unroll
    for (int cbi = 0; cbi < 4; ++cbi) {
      v8s b0 = *(const v8s*)&cB0[(wn + cbi * 16 + lrow) * 32 + fg];
#pragma unroll
      for (int mt = 0; mt < 4; ++mt)
        acc0[mt][cbi] = __builtin_amdgcn_mfma_f32_16x16x32_bf16(af[mt], b0, acc0[mt][cbi], 0, 0, 0);
      if constexpr (DUAL) {
        v8s b1 = *(const v8s*)&cB1[(wn + cbi * 16 + lrow) * 32 + fg];
#pragma unroll
        for (int mt = 0; mt < 4; ++mt)
          acc1[mt][cbi] = __builtin_amdgcn_mfma_f32_16x16x32_bf16(af[mt], b1, acc1[mt][cbi], 0, 0, 0);
      }
    }
    __builtin_amdgcn_s_setprio(0);

    if constexpr (!ABF16) {
      if (kt + 1 < NT) {
        // mid wait: retire through this iter's A reg-loads (also forces
        // B(kt+1) complete -> ready for next iter's reads)
        if (kt + 2 < NT) { if constexpr (DUAL) s_vmcnt4(); else s_vmcnt2(); }
        else { s_vmcnt0(); }
        writeAf(Abuf(kt + 1));
        s_lgkm0();  // ds_writes visible before next barrier
      }
    }
  }

  // ---- epilogue (all loads drained by final vmcnt(0)) ----
  float bv[4] = {0.f, 0.f, 0.f, 0.f};
  if constexpr (DUAL) {
#pragma unroll
    for (int cbi = 0; cbi < 4; ++cbi) bv[cbi] = bias1[wn + cbi * 16 + lrow];
  }
#pragma unroll
  for (int mt = 0; mt < 4; ++mt) {
#pragma unroll
    for (int r = 0; r < 4; ++r) {
      int gr = m0 + wm + mt * 16 + lq * 4 + r;
      if (gr < M) {
#pragma unroll
        for (int cbi = 0; cbi < 4; ++cbi) {
          int gc = wn + cbi * 16 + lrow;
          C0[(size_t)gr * 128 + gc] = f2bf(acc0[mt][cbi][r]);
          if constexpr (DUAL) C1[(size_t)gr * 128 + gc] = f2bf(acc1[mt][cbi][r] + bv[cbi]);
        }
      }
    }
  }
}

// ------------------------------------------------------------------
// fused per-layer GEMM dispatchers (segment switch on blockIdx.x)
// dynamic LDS = (2*4096 + 3*8192) shorts = 65536 bytes
// ------------------------------------------------------------------
__global__ __launch_bounds__(256, 2) void layer1_kernel(
    const float* __restrict__ xc, int Mc,
    const unsigned short* __restrict__ Bc0, const unsigned short* __restrict__ Bc1,
    unsigned short* __restrict__ y_s, unsigned short* __restrict__ h1,
    const float* __restrict__ b1s,
    const float* __restrict__ xt, int Mt, const unsigned short* __restrict__ Bt_,
    unsigned short* __restrict__ y_a,
    const float* __restrict__ xcl, int Mcl, const unsigned short* __restrict__ Bcl,
    unsigned short* __restrict__ y_t, int nbC, int nbT) {
  extern __shared__ unsigned short smem[];
  int b = blockIdx.x;
  if (b < nbC)
    gemm_body<256, true, false>(b, smem, xc, Mc, Bc0, Bc1, y_s, h1, b1s);
  else if (b < nbC + nbT)
    gemm_body<128, false, false>(b - nbC, smem, xt, Mt, Bt_, nullptr, y_a, nullptr, nullptr);
  else
    gemm_body<128, false, false>(b - nbC - nbT, smem, xcl, Mcl, Bcl, nullptr, y_t, nullptr, nullptr);
}

__global__ __launch_bounds__(256, 2) void layer2_kernel(
    unsigned short* h1, int Mc,
    const unsigned short* __restrict__ Bc0, const unsigned short* __restrict__ Bc1,
    unsigned short* __restrict__ y_s, const float* __restrict__ b2s,
    const float* __restrict__ xt, int Mt, const unsigned short* __restrict__ Bt_,
    unsigned short* __restrict__ y_a,
    const float* __restrict__ xcl, int Mcl, const unsigned short* __restrict__ Bcl,
    unsigned short* __restrict__ y_t, int nbC, int nbT) {
  extern __shared__ unsigned short smem[];
  int b = blockIdx.x;
  if (b < nbC)
    gemm_body<128, true, true>(b, smem, h1, Mc, Bc0, Bc1, y_s, h1, b2s);  // h1 already relu'd
  else if (b < nbC + nbT)
    gemm_body<128, false, false>(b - nbC, smem, xt, Mt, Bt_, nullptr, y_a, nullptr, nullptr);
  else
    gemm_body<128, false, false>(b - nbC - nbT, smem, xcl, Mcl, Bcl, nullptr, y_t, nullptr, nullptr);
}

// ------------------------------------------------------------------
// fused CSR gather, quarter-wave per edge; h is bf16 (RMW by quarter 0)
// final write applies relu (h = relu(self + aggregates)) so downstream
// GEMM/heads stages consume bf16 directly via global_load_lds.
// ------------------------------------------------------------------
__global__ __launch_bounds__(256) void gather_kernel(
    const unsigned short* __restrict__ ys, const unsigned short* __restrict__ ya,
    const unsigned short* __restrict__ yt,
    const int* __restrict__ rs_all,
    const int* __restrict__ src_s, const int* __restrict__ src_a,
    const int* __restrict__ src_t,
    const float* __restrict__ inv, unsigned short* h, int M) {
  int row = blockIdx.x * 4 + (threadIdx.x >> 6);
  if (row >= M) return;
  const int lane = threadIdx.x & 63;
  const int q = lane >> 4;
  const int col = (lane & 15) * 8;
  const int NP = M + 1;

  int b0 = rs_all[row],          e0 = rs_all[row + 1];
  int b1 = rs_all[NP + row],     e1 = rs_all[NP + row + 1];
  int b2 = rs_all[2 * NP + row], e2 = rs_all[2 * NP + row + 1];
  float sc0 = inv[row], sc1 = inv[M + row], sc2 = inv[2 * M + row];

  float acc[8];
#pragma unroll
  for (int j = 0; j < 8; ++j) acc[j] = 0.f;

  auto seg = [&](const unsigned short* __restrict__ y, const int* __restrict__ src,
                 int b, int e, float sc) {
    float s[8];
#pragma unroll
    for (int j = 0; j < 8; ++j) s[j] = 0.f;
    for (int i = b + q; i < e; i += 4) {
      int si = src[i];
      uint4 v = *(const uint4*)(y + (size_t)si * HD + col);
      s[0] += __uint_as_float(v.x << 16);
      s[1] += __uint_as_float(v.x & 0xffff0000u);
      s[2] += __uint_as_float(v.y << 16);
      s[3] += __uint_as_float(v.y & 0xffff0000u);
      s[4] += __uint_as_float(v.z << 16);
      s[5] += __uint_as_float(v.z & 0xffff0000u);
      s[6] += __uint_as_float(v.w << 16);
      s[7] += __uint_as_float(v.w & 0xffff0000u);
    }
#pragma unroll
    for (int j = 0; j < 8; ++j) acc[j] += s[j] * sc;
  };
  seg(ys, src_s, b0, e0, sc0);
  seg(ya, src_a, b1, e1, sc1);
  seg(yt, src_t, b2, e2, sc2);

#pragma unroll
  for (int j = 0; j < 8; ++j) {
    acc[j] += __shfl_xor(acc[j], 16);
    acc[j] += __shfl_xor(acc[j], 32);
  }
  if (q == 0) {
    uint4 hv = *(uint4*)(h + (size_t)row * HD + col);
    auto upd = [&](unsigned int u, float a0, float a1) {
      float lo = fmaxf(__uint_as_float(u << 16) + a0, 0.f);
      float hi = fmaxf(__uint_as_float(u & 0xffff0000u) + a1, 0.f);
      return (unsigned int)f2bf(lo) | ((unsigned int)f2bf(hi) << 16);
    };
    hv.x = upd(hv.x, acc[0], acc[1]);
    hv.y = upd(hv.y, acc[2], acc[3]);
    hv.z = upd(hv.z, acc[4], acc[5]);
    hv.w = upd(hv.w, acc[6], acc[7]);
    *(uint4*)(h + (size_t)row * HD + col) = hv;
  }
}

// ------------------------------------------------------------------
// fused heads: P = relu(h2)@Wht^T + bh (MFMA) -> LDS -> epilogue
// 64 rows/block, 4 waves; thread t<64 does row t's sigmoid/softmax/impl
// (h2 is already relu'd by gather; relu2 here is an idempotent no-op)
// ------------------------------------------------------------------
__global__ __launch_bounds__(256, 4) void heads_kernel(
    const unsigned short* __restrict__ h2b, int M,
    const unsigned short* __restrict__ Wht, const float* __restrict__ bh,
    const float* __restrict__ Wm,
    float* __restrict__ out_t, float* __restrict__ out_i,
    float* __restrict__ out_m) {
  constexpr int AST_H = 136;
  __shared__ unsigned short As[64 * AST_H];
  __shared__ float Ps[64][17];
  const int t = threadIdx.x;
  const int wave = t >> 6, lane = t & 63;
  const int m0 = blockIdx.x * 64;
  const int lrow = lane & 15, lq = lane >> 4;

#pragma unroll
  for (int j = 0; j < 4; ++j) {
    int idx = j * 256 + t;
    int row = idx >> 4;
    int c8 = idx & 15;
    int gr = m0 + row;
    uint4 v = make_uint4(0, 0, 0, 0);
    if (gr < M) v = *(const uint4*)(h2b + (size_t)gr * 128 + c8 * 8);
    v.x = relu2(v.x); v.y = relu2(v.y); v.z = relu2(v.z); v.w = relu2(v.w);
    *(uint4*)&As[row * AST_H + c8 * 8] = v;
  }
  __syncthreads();

  v4f acc = (v4f)(0.f);
#pragma unroll
  for (int ks = 0; ks < 4; ++ks) {
    v8s a = *(const v8s*)&As[(wave * 16 + lrow) * AST_H + ks * 32 + lq * 8];
    v8s b = *(const v8s*)(Wht + lrow * 128 + ks * 32 + lq * 8);
    acc = __builtin_amdgcn_mfma_f32_16x16x32_bf16(a, b, acc, 0, 0, 0);
  }
  float bv = bh[lrow];
#pragma unroll
  for (int r = 0; r < 4; ++r)
    Ps[wave * 16 + lq * 4 + r][lrow] = acc[r] + bv;
  __syncthreads();

  if (t < 64) {
    int row = m0 + t;
    if (row < M) {
      float t_[5], i_[4], mb[3];
#pragma unroll
      for (int o = 0; o < 5; ++o) t_[o] = Ps[t][o];
#pragma unroll
      for (int o = 0; o < 4; ++o) i_[o] = Ps[t][5 + o];
#pragma unroll
      for (int o = 0; o < 3; ++o) mb[o] = Ps[t][9 + o];
      float tp[5];
#pragma unroll
      for (int o = 0; o < 5; ++o) tp[o] = 1.f / (1.f + __expf(-t_[o]));
      float mx = fmaxf(fmaxf(i_[0], i_[1]), fmaxf(i_[2], i_[3]));
      float ex[4], es = 0.f;
#pragma unroll
      for (int o = 0; o < 4; ++o) { ex[o] = __expf(i_[o] - mx); es += ex[o]; }
      float inv_es = 1.f / es;
      float ml[3];
#pragma unroll
      for (int o = 0; o < 3; ++o) {
        float v = mb[o];
#pragma unroll
        for (int j = 0; j < 5; ++j) v += tp[j] * Wm[(128 + j) * 3 + o];
#pragma unroll
        for (int j = 0; j < 4; ++j) v += (ex[j] * inv_es) * Wm[(133 + j) * 3 + o];
        ml[o] = v;
      }
#pragma unroll
      for (int o = 0; o < 5; ++o) out_t[(size_t)row * 5 + o] = t_[o];
#pragma unroll
      for (int o = 0; o < 4; ++o) out_i[(size_t)row * 4 + o] = i_[o];
#pragma unroll
      for (int o = 0; o < 3; ++o) out_m[(size_t)row * 3 + o] = ml[o];
    }
  }
}

// ------------------------------------------------------------------
extern "C" void kernel_launch(void* const* d_in, const int* in_sizes, int n_in,
                              void* d_out, int out_size, void* d_ws, size_t ws_size,
                              hipStream_t stream) {
  const float* x_comment = (const float*)d_in[0];
  const float* x_topic   = (const float*)d_in[1];
  const float* x_claim   = (const float*)d_in[2];
  const float* c1s_Wl = (const float*)d_in[3];
  const float* c1s_bl = (const float*)d_in[4];
  const float* c1s_Wr = (const float*)d_in[5];
  const float* c1a_Wl = (const float*)d_in[6];
  const float* c1a_bl = (const float*)d_in[7];
  const float* c1a_Wr = (const float*)d_in[8];
  const float* c1t_Wl = (const float*)d_in[9];
  const float* c1t_bl = (const float*)d_in[10];
  const float* c1t_Wr = (const float*)d_in[11];
  const float* c2s_Wl = (const float*)d_in[12];
  const float* c2s_bl = (const float*)d_in[13];
  const float* c2s_Wr = (const float*)d_in[14];
  const float* c2a_Wl = (const float*)d_in[15];
  const float* c2a_bl = (const float*)d_in[16];
  const float* c2a_Wr = (const float*)d_in[17];
  const float* c2t_Wl = (const float*)d_in[18];
  const float* c2t_bl = (const float*)d_in[19];
  const float* c2t_Wr = (const float*)d_in[20];
  const float* Wt = (const float*)d_in[21];
  const float* bt = (const float*)d_in[22];
  const float* Wi = (const float*)d_in[23];
  const float* bi = (const float*)d_in[24];
  const float* Wm = (const float*)d_in[25];
  const float* bm = (const float*)d_in[26];
  const int* ei_sim = (const int*)d_in[27];
  const int* ei_ab  = (const int*)d_in[28];
  const int* ei_tg  = (const int*)d_in[29];

  const int E_sim = in_sizes[27] / 2;
  const int E_ab  = in_sizes[28] / 2;
  const int E_tg  = in_sizes[29] / 2;
  const int N_T = in_sizes[1] / 128;
  const int N_CL = in_sizes[2] / 128;

  float* ws = (float*)d_ws;
  unsigned short* h1 = (unsigned short*)ws;                // 100000*128 bf16
  unsigned short* y_s = (unsigned short*)(ws + 12800000);  // 100000*128 bf16
  unsigned short* y_a = (unsigned short*)(ws + 19200000);  // 5000*128 bf16
  unsigned short* y_t = (unsigned short*)(ws + 19520000);  // 20000*128 bf16
  int*   cnt    = (int*)(ws + 20800000);                   // 3*N_C
  float* inv    = ws + 21100000;                           // 3*N_C
  int*   rs_all = (int*)(ws + 21400000);                   // 3*(N_C+1)
  int*   src_s  = (int*)(ws + 21700016);                   // E_sim
  int*   src_a  = (int*)(ws + 22300016);                   // E_ab
  int*   src_t  = (int*)(ws + 22600016);                   // E_tg
  int*   part   = (int*)(ws + 22900016);                   // 3*128
  float* b1s    = ws + 22900416;
  float* b2s    = ws + 22900544;
  unsigned short* Bt_c1s = (unsigned short*)(ws + 22900672);  // 128x256
  unsigned short* Bt_W1s = Bt_c1s + 32768;                    // 128x256
  unsigned short* Bt_c1a = Bt_W1s + 32768;                    // 128x128
  unsigned short* Bt_c1t = Bt_c1a + 16384;
  unsigned short* Bt_c2s = Bt_c1t + 16384;
  unsigned short* Bt_W2s = Bt_c2s + 16384;
  unsigned short* Bt_c2a = Bt_W2s + 16384;
  unsigned short* Bt_c2t = Bt_c2a + 16384;
  unsigned short* Wht = (unsigned short*)(ws + 24600000);     // 16x128 bf16
  float* bh     = ws + 24601100;                              // 16

  const int nbS = (N_C + SCAN_CHUNK - 1) / SCAN_CHUNK;
  const int ebx = (E_sim + 255) / 256;
  const int nbC = (N_C + 127) / 128;
  const int nbT = (N_T + 127) / 128;
  const int nbCl = (N_CL + 127) / 128;
  const size_t lds_bytes = (2 * 4096 + 3 * 8192) * sizeof(unsigned short);  // 65536

  // ---- weight prep ----
  prep_weights<<<dim3(128, 10), 256, 0, stream>>>(
      c1s_Wl, c1s_Wr, c1a_Wr, c1t_Wr, c1a_Wl, c1t_Wl,
      c2s_Wl, c2s_Wr, c2a_Wr, c2t_Wr, c2a_Wl, c2t_Wl,
      c1s_bl, c1a_bl, c1t_bl, c2s_bl, c2a_bl, c2t_bl,
      Wt, bt, Wi, bi, Wm, bm,
      Bt_c1s, Bt_W1s, Bt_c1a, Bt_c1t, Bt_c2s, Bt_W2s, Bt_c2a, Bt_c2t,
      Wht, b1s, b2s, bh);

  // ---- degree histogram + CSR build ----
  hipMemsetAsync(cnt, 0, 3 * N_C * sizeof(int), stream);
  count3_kernel<<<dim3(ebx, 3), 256, 0, stream>>>(ei_sim, E_sim, ei_ab, E_ab, ei_tg, E_tg, cnt);
  scan_phaseA<<<dim3(nbS, 3), 256, 0, stream>>>(cnt, part, inv, N_C);
  scan_phaseB<<<dim3(1, 3), 256, 0, stream>>>(part, nbS);
  scan_phaseC<<<dim3(nbS, 3), 256, 0, stream>>>(cnt, part, rs_all, N_C);
  set_totals<<<1, 64, 0, stream>>>(rs_all, E_sim, E_ab, E_tg, N_C);
  place3_kernel<<<dim3(ebx, 3), 256, 0, stream>>>(
      ei_sim, E_sim, ei_ab, E_ab, ei_tg, E_tg, rs_all, cnt, src_s, src_a, src_t, N_C);

  // ---------------- layer 1 (fused 3 GEMMs) ----------------
  layer1_kernel<<<nbC + nbT + nbCl, 256, lds_bytes, stream>>>(
      x_comment, N_C, Bt_c1s, Bt_W1s, y_s, h1, b1s,
      x_topic, N_T, Bt_c1a, y_a,
      x_claim, N_CL, Bt_c1t, y_t, nbC, nbT);

  gather_kernel<<<(N_C + 3) / 4, 256, 0, stream>>>(
      y_s, y_a, y_t, rs_all, src_s, src_a, src_t, inv, h1, N_C);

  // ---------------- layer 2 (fused 3 GEMMs, h in-place bf16) --------
  layer2_kernel<<<nbC + nbT + nbCl, 256, lds_bytes, stream>>>(
      h1, N_C, Bt_c2s, Bt_W2s, y_s, b2s,
      x_topic, N_T, Bt_c2a, y_a,
      x_claim, N_CL, Bt_c2t, y_t, nbC, nbT);

  gather_kernel<<<(N_C + 3) / 4, 256, 0, stream>>>(
      y_s, y_a, y_t, rs_all, src_s, src_a, src_t, inv, h1, N_C);

  // ---------------- heads (fully fused) ----------------
  float* out = (float*)d_out;
  heads_kernel<<<(N_C + 63) / 64, 256, 0, stream>>>(
      h1, N_C, Wht, bh, Wm,
      out, out + (size_t)N_C * 5, out + (size_t)N_C * 9);
}

// Round 3
// 500.354 us; speedup vs baseline: 1.0821x; 1.0473x over previous
//
#include <hip/hip_runtime.h>
#include <math.h>

#define N_C 100000
#define HD 128
#define SCAN_CHUNK 1024

typedef short v8s __attribute__((ext_vector_type(8)));
typedef float v4f __attribute__((ext_vector_type(4)));
typedef __attribute__((address_space(1))) const void gas_t;
typedef __attribute__((address_space(3))) void las_t;

__device__ __forceinline__ unsigned short f2bf(float f) {
  unsigned int u = __float_as_uint(f);
  u += 0x7fffu + ((u >> 16) & 1u);
  return (unsigned short)(u >> 16);
}

// exact relu on two packed bf16 halves (negative & -0 -> +0)
__device__ __forceinline__ unsigned int relu2(unsigned int u) {
  unsigned int m = ((u & 0x80008000u) >> 15) * 0xFFFFu;
  return u & ~m;
}

// counted-wait helper: n is compile-time-foldable at every call site
// (kt fully unrolled); each branch holds a literal immediate.
__device__ __forceinline__ void vmcnt_sel(int n) {
  if (n == 8)      asm volatile("s_waitcnt vmcnt(8)" ::: "memory");
  else if (n == 6) asm volatile("s_waitcnt vmcnt(6)" ::: "memory");
  else if (n == 4) asm volatile("s_waitcnt vmcnt(4)" ::: "memory");
  else if (n == 2) asm volatile("s_waitcnt vmcnt(2)" ::: "memory");
  else             asm volatile("s_waitcnt vmcnt(0)" ::: "memory");
}
__device__ __forceinline__ void s_lgkm0() { asm volatile("s_waitcnt lgkmcnt(0)" ::: "memory"); }
__device__ __forceinline__ void s_bar() { __builtin_amdgcn_s_barrier(); }

// ------------------------------------------------------------------
// fused prep kernels
// ------------------------------------------------------------------
__global__ void count3_kernel(const int* __restrict__ ei_s, int Es,
                              const int* __restrict__ ei_a, int Ea,
                              const int* __restrict__ ei_t, int Et,
                              int* __restrict__ cnt) {
  int e = blockIdx.x * 256 + threadIdx.x;
  int y = blockIdx.y;
  if (y == 0) {
    if (e < Es) atomicAdd(&cnt[ei_s[Es + e]], 1);
  } else if (y == 1) {
    if (e < Ea) atomicAdd(&cnt[N_C + ei_a[Ea + e]], 1);
  } else {
    if (e < Et) atomicAdd(&cnt[2 * N_C + ei_t[Et + e]], 1);
  }
}

// merged placement: srcm[p] = (src + arena_row_offset) | (seg << 28)
__global__ void place3_kernel(const int* __restrict__ ei_s, int Es,
                              const int* __restrict__ ei_a, int Ea,
                              const int* __restrict__ ei_t, int Et,
                              const int* __restrict__ base, int* __restrict__ fill,
                              unsigned int* __restrict__ srcm,
                              int offA, int offT, int n) {
  int e = blockIdx.x * 256 + threadIdx.x;
  int y = blockIdx.y;
  const int* ei; int E; unsigned roff;
  if (y == 0)      { ei = ei_s; E = Es; roff = 0u; }
  else if (y == 1) { ei = ei_a; E = Ea; roff = (unsigned)offA; }
  else             { ei = ei_t; E = Et; roff = (unsigned)offT; }
  if (e < E) {
    int d = ei[E + e];
    int p = base[y * n + d] + atomicAdd(&fill[y * n + d], 1);
    srcm[p] = ((unsigned)ei[e] + roff) | ((unsigned)y << 28);
  }
}

// ------------------------------------------------------------------
// merged 3-phase exclusive scan over c0+c1+c2; phaseA emits inv (all 3
// segs), phaseC zeroes cnt (fill reuse) and emits merged row-ptr rs_m
// plus per-(seg,row) placement bases.
// ------------------------------------------------------------------
__global__ __launch_bounds__(256) void scan_phaseA(const int* __restrict__ cnt,
                                                   int* __restrict__ partial,
                                                   float* __restrict__ inv, int n) {
  __shared__ int sdata[256];
  int base_i = blockIdx.x * SCAN_CHUNK + threadIdx.x * 4;
  int s = 0;
#pragma unroll
  for (int j = 0; j < 4; ++j) {
    int idx = base_i + j;
    if (idx < n) {
      int c0 = cnt[idx], c1 = cnt[n + idx], c2 = cnt[2 * n + idx];
      s += c0 + c1 + c2;
      inv[idx] = 1.0f / fmaxf((float)c0, 1.0f);
      inv[n + idx] = 1.0f / fmaxf((float)c1, 1.0f);
      inv[2 * n + idx] = 1.0f / fmaxf((float)c2, 1.0f);
    }
  }
  sdata[threadIdx.x] = s;
  __syncthreads();
  for (int off = 128; off > 0; off >>= 1) {
    if (threadIdx.x < off) sdata[threadIdx.x] += sdata[threadIdx.x + off];
    __syncthreads();
  }
  if (threadIdx.x == 0) partial[blockIdx.x] = sdata[0];
}

__global__ __launch_bounds__(256) void scan_phaseB(int* __restrict__ partial, int nb) {
  __shared__ int sdata[256];
  int t = threadIdx.x;
  int v = (t < nb) ? partial[t] : 0;
  sdata[t] = v;
  __syncthreads();
  for (int off = 1; off < 256; off <<= 1) {
    int x = (t >= off) ? sdata[t - off] : 0;
    __syncthreads();
    sdata[t] += x;
    __syncthreads();
  }
  if (t < nb) partial[t] = sdata[t] - v;
}

__global__ __launch_bounds__(256) void scan_phaseC(int* __restrict__ cnt,
                                                   const int* __restrict__ partial,
                                                   int* __restrict__ rs_m,
                                                   int* __restrict__ base, int n) {
  __shared__ int sdata[256];
  int t = threadIdx.x;
  int base_i = blockIdx.x * SCAN_CHUNK + t * 4;
  int c0[4], c1[4], v[4];
  int s = 0;
#pragma unroll
  for (int j = 0; j < 4; ++j) {
    int idx = base_i + j;
    int a = 0, b = 0, c = 0;
    if (idx < n) {
      a = cnt[idx]; b = cnt[n + idx]; c = cnt[2 * n + idx];
      cnt[idx] = 0; cnt[n + idx] = 0; cnt[2 * n + idx] = 0;  // fill reuse
    }
    c0[j] = a; c1[j] = b;
    v[j] = a + b + c;
    s += v[j];
  }
  sdata[t] = s;
  __syncthreads();
  for (int off = 1; off < 256; off <<= 1) {
    int x = (t >= off) ? sdata[t - off] : 0;
    __syncthreads();
    sdata[t] += x;
    __syncthreads();
  }
  int run = sdata[t] - s + partial[blockIdx.x];
#pragma unroll
  for (int j = 0; j < 4; ++j) {
    int idx = base_i + j;
    if (idx < n) {
      rs_m[idx] = run;
      base[idx] = run;
      base[n + idx] = run + c0[j];
      base[2 * n + idx] = run + c0[j] + c1[j];
    }
    run += v[j];
  }
}

__global__ void set_totals(int* rs_m, int Etot, int n) {
  if (threadIdx.x == 0) rs_m[n] = Etot;
}

// ------------------------------------------------------------------
// single prep kernel: weight transposes+cvt (y=0..7), biases (y=8),
// packed head weight (y=9). grid (128, 10) x 256
// ------------------------------------------------------------------
__global__ void prep_weights(
    const float* __restrict__ c1s_Wl, const float* __restrict__ c1s_Wr,
    const float* __restrict__ c1a_Wr, const float* __restrict__ c1t_Wr,
    const float* __restrict__ c1a_Wl, const float* __restrict__ c1t_Wl,
    const float* __restrict__ c2s_Wl, const float* __restrict__ c2s_Wr,
    const float* __restrict__ c2a_Wr, const float* __restrict__ c2t_Wr,
    const float* __restrict__ c2a_Wl, const float* __restrict__ c2t_Wl,
    const float* __restrict__ c1s_bl, const float* __restrict__ c1a_bl,
    const float* __restrict__ c1t_bl, const float* __restrict__ c2s_bl,
    const float* __restrict__ c2a_bl, const float* __restrict__ c2t_bl,
    const float* __restrict__ Wt, const float* __restrict__ bt,
    const float* __restrict__ Wi, const float* __restrict__ bi,
    const float* __restrict__ Wm, const float* __restrict__ bm,
    unsigned short* __restrict__ Bt_c1s, unsigned short* __restrict__ Bt_W1s,
    unsigned short* __restrict__ Bt_c1a, unsigned short* __restrict__ Bt_c1t,
    unsigned short* __restrict__ Bt_c2s, unsigned short* __restrict__ Bt_W2s,
    unsigned short* __restrict__ Bt_c2a, unsigned short* __restrict__ Bt_c2t,
    unsigned short* __restrict__ Wht,
    float* __restrict__ b1s, float* __restrict__ b2s, float* __restrict__ bh) {
  int y = blockIdx.y;
  int idx = blockIdx.x * 256 + threadIdx.x;
  if (y == 8) {
    if (blockIdx.x == 0) {
      int t = threadIdx.x;
      if (t < 128) b1s[t] = c1s_bl[t] + c1a_bl[t] + c1t_bl[t];
      else b2s[t - 128] = c2s_bl[t - 128] + c2a_bl[t - 128] + c2t_bl[t - 128];
    } else if (blockIdx.x == 1) {
      int t = threadIdx.x;
      if (t < 16) {
        float v = 0.f;
        if (t < 5) v = bt[t];
        else if (t < 9) v = bi[t - 5];
        else if (t < 12) v = bm[t - 9];
        bh[t] = v;
      }
    }
    return;
  }
  if (y == 9) {
    if (idx < 16 * 128) {
      int o = idx >> 7, k = idx & 127;
      float v = 0.f;
      if (o < 5) v = Wt[k * 5 + o];
      else if (o < 9) v = Wi[k * 4 + (o - 5)];
      else if (o < 12) v = Wm[k * 3 + (o - 9)];
      Wht[o * 128 + k] = f2bf(v);
    }
    return;
  }
  int K = (y < 2) ? 256 : 128;
  if (idx >= K * 128) return;
  int k = idx >> 7, n = idx & 127;
  float v;
  unsigned short* out;
  switch (y) {
    case 0: v = c1s_Wl[idx]; out = Bt_c1s; break;
    case 1: v = c1s_Wr[idx] + c1a_Wr[idx] + c1t_Wr[idx]; out = Bt_W1s; break;
    case 2: v = c1a_Wl[idx]; out = Bt_c1a; break;
    case 3: v = c1t_Wl[idx]; out = Bt_c1t; break;
    case 4: v = c2s_Wl[idx]; out = Bt_c2s; break;
    case 5: v = c2s_Wr[idx] + c2a_Wr[idx] + c2t_Wr[idx]; out = Bt_W2s; break;
    case 6: v = c2a_Wl[idx]; out = Bt_c2a; break;
    default: v = c2t_Wl[idx]; out = Bt_c2t; break;
  }
  out[n * K + k] = f2bf(v);
}

// ------------------------------------------------------------------
// GEMM body, A-deep counted-vmcnt pipeline:
//   C0(bf16) = A@B0 [, C1(bf16) = A@B1 + bias1]
// tile 128x128, 4 waves 2x2, BK=32, mfma 16x16x32 bf16.
// A is the HBM stream -> depth 2 (3 LDS bufs; fp32: 2 reg-sets loaded
// 2 tiles ahead, ds_write 1 ahead; bf16: DMA 2 ahead).
// B is an L2-resident panel -> depth 1 (2 LDS bufs, DMA 1 ahead).
// LDS = 3*8KB (A) + 2*16KB (B0+B1) = 56KB -> 2 blocks/CU.
// Per-iter issue order: B(kt+1) then A(kt+2); top-wait vmcnt(nA)
// retires B(kt)+A(kt) while A(kt+2) stays in flight (~2 iters cover).
// fp32 mid-wait vmcnt(nB [+nA]) retires A(kt+1) reg-loads before the
// ds_write. vmcnt(0) only on the last iteration.
// A/C1 may alias (layer-2 in-place): block reads only its own 128 rows,
// all loads drained before epilogue stores.
// ------------------------------------------------------------------
template <int KD, bool DUAL, bool ABF16>
__device__ __forceinline__ void gemm_body(
    int bx, unsigned short* smem, const void* Av, int M,
    const unsigned short* __restrict__ B0t, const unsigned short* __restrict__ B1t,
    unsigned short* __restrict__ C0, unsigned short* C1,
    const float* __restrict__ bias1) {
  constexpr int NT = KD / 32;
  constexpr int nA = ABF16 ? 2 : 4;   // vmem ops per A tile (per thread)
  constexpr int nB = DUAL ? 4 : 2;    // vmem ops per B tile (per thread)
  const int t = threadIdx.x;
  const int wave = t >> 6, lane = t & 63;
  const int wm = (wave & 1) * 64;
  const int wn = (wave >> 1) * 64;
  const int m0 = bx * 128;
  const int lrow = lane & 15, lq = lane >> 4;
  // swizzled fragment col offset (shorts): slot = lq ^ ((row>>1)&3)
  const int fg = (lq ^ ((lrow >> 1) & 3)) * 8;
  // gload_lds staging lane constants: 1KB chunk = 16 rows x 64B
  const int sr = lane >> 2;                        // row within chunk
  const int sg = (lane & 3) ^ ((lane >> 3) & 3);   // swizzled source col-group

  const float* Af = (const float*)Av;
  const unsigned short* Ab_g = (const unsigned short*)Av;

  auto Abuf = [&](int i) { return smem + (i % 3) * 4096; };
  auto Bbuf = [&](int i) { return smem + 12288 + (i & 1) * 8192; };

  v4f acc0[4][4];
  v4f acc1[DUAL ? 4 : 1][DUAL ? 4 : 1];
#pragma unroll
  for (int i = 0; i < 4; ++i)
#pragma unroll
    for (int j = 0; j < 4; ++j) acc0[i][j] = (v4f)(0.f);
  if constexpr (DUAL) {
#pragma unroll
    for (int i = 0; i < 4; ++i)
#pragma unroll
      for (int j = 0; j < 4; ++j) acc1[i][j] = (v4f)(0.f);
  }

  float4 ar0[4], ar1[4];  // fp32-A staging reg-sets (2 x 16 VGPR)

  auto stageB1 = [&](const unsigned short* __restrict__ Bt, unsigned short* lds, int k0) {
#pragma unroll
    for (int j = 0; j < 2; ++j) {
      int cidx = j * 4 + wave;
      const unsigned short* src = Bt + (size_t)(cidx * 16 + sr) * KD + k0 + sg * 8;
      __builtin_amdgcn_global_load_lds((gas_t*)src, (las_t*)(lds + cidx * 512), 16, 0, 0);
    }
  };
  auto stageB2 = [&](unsigned short* ldsB, int k0) {
    stageB1(B0t, ldsB, k0);
    if constexpr (DUAL) stageB1(B1t, ldsB + 4096, k0);
  };
  auto stageAb = [&](unsigned short* lds, int k0) {
#pragma unroll
    for (int j = 0; j < 2; ++j) {
      int cidx = j * 4 + wave;
      int gr = m0 + cidx * 16 + sr;
      if (gr >= M) gr = M - 1;  // clamp: OOB rows read garbage, never written back
      const unsigned short* src = Ab_g + (size_t)gr * KD + k0 + sg * 8;
      __builtin_amdgcn_global_load_lds((gas_t*)src, (las_t*)(lds + cidx * 512), 16, 0, 0);
    }
  };
  auto loadAf = [&](int k0, float4* ar) {
    int r = t >> 1, h = t & 1;
    int gr = m0 + r;
    if (gr < M) {
      const float* src = Af + (size_t)gr * KD + k0 + h * 16;
#pragma unroll
      for (int j = 0; j < 4; ++j) ar[j] = *(const float4*)(src + j * 4);
    } else {
#pragma unroll
      for (int j = 0; j < 4; ++j) ar[j] = make_float4(0.f, 0.f, 0.f, 0.f);
    }
  };
  auto writeAf = [&](const float4* ar, unsigned short* lds) {
    int r = t >> 1, h = t & 1;
    int sw = (r >> 1) & 3;
    auto pk = [](float a, float b) {
      return (unsigned int)f2bf(a) | ((unsigned int)f2bf(b) << 16);
    };
    uint4 w0 = make_uint4(pk(ar[0].x, ar[0].y), pk(ar[0].z, ar[0].w),
                          pk(ar[1].x, ar[1].y), pk(ar[1].z, ar[1].w));
    uint4 w1 = make_uint4(pk(ar[2].x, ar[2].y), pk(ar[2].z, ar[2].w),
                          pk(ar[3].x, ar[3].y), pk(ar[3].z, ar[3].w));
    *(uint4*)&lds[r * 32 + ((2 * h) ^ sw) * 8] = w0;
    *(uint4*)&lds[r * 32 + ((2 * h + 1) ^ sw) * 8] = w1;
  };

  // ---- prologue: queue order A(0), B(0), A(1) ----
  if constexpr (ABF16) {
    stageAb(Abuf(0), 0);
    stageB2(Bbuf(0), 0);
    stageAb(Abuf(1), 32);
  } else {
    loadAf(0, ar0);
    stageB2(Bbuf(0), 0);
    loadAf(32, ar1);
    vmcnt_sel(nA + nB);  // retire A(0) regs; B(0)+A(1) stay in flight
    writeAf(ar0, Abuf(0));
    s_lgkm0();
  }

#pragma unroll
  for (int kt = 0; kt < NT; ++kt) {
    // top wait: retire through B(kt) (and A(kt)); A(kt+1..2) stay in flight
    vmcnt_sel((kt + 1 < NT) ? nA : 0);
    s_bar();  // tile kt fully in LDS; all waves done reading old bufs

    if (kt + 1 < NT) stageB2(Bbuf(kt + 1), (kt + 1) * 32);
    if (kt + 2 < NT) {
      if constexpr (ABF16) stageAb(Abuf(kt + 2), (kt + 2) * 32);
      else loadAf((kt + 2) * 32, ((kt & 1) == 0) ? ar0 : ar1);
    }

    unsigned short* cAs = Abuf(kt);
    unsigned short* cB0 = Bbuf(kt);
    unsigned short* cB1 = cB0 + 4096;
    v8s af[4];
#pragma unroll
    for (int mt = 0; mt < 4; ++mt)
      af[mt] = *(const v8s*)&cAs[(wm + mt * 16 + lrow) * 32 + fg];
    __builtin_amdgcn_s_setprio(1);
#pragma unroll
    for (int cbi = 0; cbi < 4; ++cbi) {
      v8s b0 = *(const v8s*)&cB0[(wn + cbi * 16 + lrow) * 32 + fg];
#pragma unroll
      for (int mt = 0; mt < 4; ++mt)
        acc0[mt][cbi] = __builtin_amdgcn_mfma_f32_16x16x32_bf16(af[mt], b0, acc0[mt][cbi], 0, 0, 0);
      if constexpr (DUAL) {
        v8s b1 = *(const v8s*)&cB1[(wn + cbi * 16 + lrow) * 32 + fg];
#pragma unroll
        for (int mt = 0; mt < 4; ++mt)
          acc1[mt][cbi] = __builtin_amdgcn_mfma_f32_16x16x32_bf16(af[mt], b1, acc1[mt][cbi], 0, 0, 0);
      }
    }
    __builtin_amdgcn_s_setprio(0);

    if constexpr (!ABF16) {
      if (kt + 1 < NT) {
        // retire A(kt+1) reg-loads; B(kt+1) [+A(kt+2)] stay in flight
        vmcnt_sel(nB + ((kt + 2 < NT) ? nA : 0));
        writeAf(((kt & 1) == 0) ? ar1 : ar0, Abuf(kt + 1));
        s_lgkm0();  // ds_writes visible before next barrier
      }
    }
  }

  // ---- epilogue (all loads drained by final vmcnt(0)) ----
  float bv[4] = {0.f, 0.f, 0.f, 0.f};
  if constexpr (DUAL) {
#pragma unroll
    for (int cbi = 0; cbi < 4; ++cbi) bv[cbi] = bias1[wn + cbi * 16 + lrow];
  }
#pragma unroll
  for (int mt = 0; mt < 4; ++mt) {
#pragma unroll
    for (int r = 0; r < 4; ++r) {
      int gr = m0 + wm + mt * 16 + lq * 4 + r;
      if (gr < M) {
#pragma unroll
        for (int cbi = 0; cbi < 4; ++cbi) {
          int gc = wn + cbi * 16 + lrow;
          C0[(size_t)gr * 128 + gc] = f2bf(acc0[mt][cbi][r]);
          if constexpr (DUAL) C1[(size_t)gr * 128 + gc] = f2bf(acc1[mt][cbi][r] + bv[cbi]);
        }
      }
    }
  }
}

// ------------------------------------------------------------------
// fused per-layer GEMM dispatchers (segment switch on blockIdx.x)
// dynamic LDS = (3*4096 + 2*8192) shorts = 57344 bytes
// ------------------------------------------------------------------
__global__ __launch_bounds__(256, 2) void layer1_kernel(
    const float* __restrict__ xc, int Mc,
    const unsigned short* __restrict__ Bc0, const unsigned short* __restrict__ Bc1,
    unsigned short* __restrict__ y_s, unsigned short* __restrict__ h1,
    const float* __restrict__ b1s,
    const float* __restrict__ xt, int Mt, const unsigned short* __restrict__ Bt_,
    unsigned short* __restrict__ y_a,
    const float* __restrict__ xcl, int Mcl, const unsigned short* __restrict__ Bcl,
    unsigned short* __restrict__ y_t, int nbC, int nbT) {
  extern __shared__ unsigned short smem[];
  int b = blockIdx.x;
  if (b < nbC)
    gemm_body<256, true, false>(b, smem, xc, Mc, Bc0, Bc1, y_s, h1, b1s);
  else if (b < nbC + nbT)
    gemm_body<128, false, false>(b - nbC, smem, xt, Mt, Bt_, nullptr, y_a, nullptr, nullptr);
  else
    gemm_body<128, false, false>(b - nbC - nbT, smem, xcl, Mcl, Bcl, nullptr, y_t, nullptr, nullptr);
}

__global__ __launch_bounds__(256, 2) void layer2_kernel(
    unsigned short* h1, int Mc,
    const unsigned short* __restrict__ Bc0, const unsigned short* __restrict__ Bc1,
    unsigned short* __restrict__ y_s, const float* __restrict__ b2s,
    const float* __restrict__ xt, int Mt, const unsigned short* __restrict__ Bt_,
    unsigned short* __restrict__ y_a,
    const float* __restrict__ xcl, int Mcl, const unsigned short* __restrict__ Bcl,
    unsigned short* __restrict__ y_t, int nbC, int nbT) {
  extern __shared__ unsigned short smem[];
  int b = blockIdx.x;
  if (b < nbC)
    gemm_body<128, true, true>(b, smem, h1, Mc, Bc0, Bc1, y_s, h1, b2s);  // h1 already relu'd
  else if (b < nbC + nbT)
    gemm_body<128, false, false>(b - nbC, smem, xt, Mt, Bt_, nullptr, y_a, nullptr, nullptr);
  else
    gemm_body<128, false, false>(b - nbC - nbT, smem, xcl, Mcl, Bcl, nullptr, y_t, nullptr, nullptr);
}

// ------------------------------------------------------------------
// fused CSR gather over the MERGED per-row edge list. One wave per row,
// quarter-wave strides the row's edges. Uniform trip count per wave
// (no divergence); 2-deep software pipeline: at iter j the row-load for
// j+1 and the index-load for j+2 are already in flight. Per-edge scale
// (seg tag in bits 28+) via cndmask + fma. h RMW applies relu.
// ------------------------------------------------------------------
__global__ __launch_bounds__(256) void gather_kernel(
    const unsigned short* __restrict__ yall,
    const int* __restrict__ rs_m, const unsigned int* __restrict__ srcm,
    const float* __restrict__ inv, unsigned short* h, int M) {
  int row = blockIdx.x * 4 + (threadIdx.x >> 6);
  if (row >= M) return;
  const int lane = threadIdx.x & 63;
  const int q = lane >> 4;
  const int col = (lane & 15) * 8;

  int mb = rs_m[row], me = rs_m[row + 1];
  float sc0 = inv[row], sc1 = inv[M + row], sc2 = inv[2 * M + row];

  // issue the h RMW read early (independent of the loop)
  uint4 hv = *(const uint4*)(h + (size_t)row * HD + col);

  float a0 = 0.f, a1 = 0.f, a2 = 0.f, a3 = 0.f;
  float a4 = 0.f, a5 = 0.f, a6 = 0.f, a7 = 0.f;

  if (me > mb) {
    const int last = me - 1;
    const int ntrip = (me - mb + 3) >> 2;  // wave-uniform
    int i = mb + q;
    unsigned ec = srcm[min(i, last)];
    uint4 vc = *(const uint4*)(yall + (size_t)(ec & 0x0FFFFFFFu) * HD + col);
    unsigned en = (ntrip > 1) ? srcm[min(i + 4, last)] : ec;
    for (int j = 0; j < ntrip; ++j) {
      unsigned ecur = ec;
      uint4 v = vc;
      if (j + 1 < ntrip) {
        vc = *(const uint4*)(yall + (size_t)(en & 0x0FFFFFFFu) * HD + col);
        ec = en;
        if (j + 2 < ntrip) en = srcm[min(i + 8, last)];
      }
      int sg = ecur >> 28;
      float s = (i < me) ? (sg == 0 ? sc0 : (sg == 1 ? sc1 : sc2)) : 0.f;
      a0 = fmaf(__uint_as_float(v.x << 16), s, a0);
      a1 = fmaf(__uint_as_float(v.x & 0xffff0000u), s, a1);
      a2 = fmaf(__uint_as_float(v.y << 16), s, a2);
      a3 = fmaf(__uint_as_float(v.y & 0xffff0000u), s, a3);
      a4 = fmaf(__uint_as_float(v.z << 16), s, a4);
      a5 = fmaf(__uint_as_float(v.z & 0xffff0000u), s, a5);
      a6 = fmaf(__uint_as_float(v.w << 16), s, a6);
      a7 = fmaf(__uint_as_float(v.w & 0xffff0000u), s, a7);
      i += 4;
    }
  }

  a0 += __shfl_xor(a0, 16); a0 += __shfl_xor(a0, 32);
  a1 += __shfl_xor(a1, 16); a1 += __shfl_xor(a1, 32);
  a2 += __shfl_xor(a2, 16); a2 += __shfl_xor(a2, 32);
  a3 += __shfl_xor(a3, 16); a3 += __shfl_xor(a3, 32);
  a4 += __shfl_xor(a4, 16); a4 += __shfl_xor(a4, 32);
  a5 += __shfl_xor(a5, 16); a5 += __shfl_xor(a5, 32);
  a6 += __shfl_xor(a6, 16); a6 += __shfl_xor(a6, 32);
  a7 += __shfl_xor(a7, 16); a7 += __shfl_xor(a7, 32);

  if (q == 0) {
    auto upd = [&](unsigned int u, float x0, float x1) {
      float lo = fmaxf(__uint_as_float(u << 16) + x0, 0.f);
      float hi = fmaxf(__uint_as_float(u & 0xffff0000u) + x1, 0.f);
      return (unsigned int)f2bf(lo) | ((unsigned int)f2bf(hi) << 16);
    };
    hv.x = upd(hv.x, a0, a1);
    hv.y = upd(hv.y, a2, a3);
    hv.z = upd(hv.z, a4, a5);
    hv.w = upd(hv.w, a6, a7);
    *(uint4*)(h + (size_t)row * HD + col) = hv;
  }
}

// ------------------------------------------------------------------
// fused heads: P = relu(h2)@Wht^T + bh (MFMA) -> LDS -> epilogue
// 64 rows/block, 4 waves; thread t<64 does row t's sigmoid/softmax/impl
// (h2 is already relu'd by gather; relu2 here is an idempotent no-op)
// ------------------------------------------------------------------
__global__ __launch_bounds__(256, 4) void heads_kernel(
    const unsigned short* __restrict__ h2b, int M,
    const unsigned short* __restrict__ Wht, const float* __restrict__ bh,
    const float* __restrict__ Wm,
    float* __restrict__ out_t, float* __restrict__ out_i,
    float* __restrict__ out_m) {
  constexpr int AST_H = 136;
  __shared__ unsigned short As[64 * AST_H];
  __shared__ float Ps[64][17];
  const int t = threadIdx.x;
  const int wave = t >> 6, lane = t & 63;
  const int m0 = blockIdx.x * 64;
  const int lrow = lane & 15, lq = lane >> 4;

#pragma unroll
  for (int j = 0; j < 4; ++j) {
    int idx = j * 256 + t;
    int row = idx >> 4;
    int c8 = idx & 15;
    int gr = m0 + row;
    uint4 v = make_uint4(0, 0, 0, 0);
    if (gr < M) v = *(const uint4*)(h2b + (size_t)gr * 128 + c8 * 8);
    v.x = relu2(v.x); v.y = relu2(v.y); v.z = relu2(v.z); v.w = relu2(v.w);
    *(uint4*)&As[row * AST_H + c8 * 8] = v;
  }
  __syncthreads();

  v4f acc = (v4f)(0.f);
#pragma unroll
  for (int ks = 0; ks < 4; ++ks) {
    v8s a = *(const v8s*)&As[(wave * 16 + lrow) * AST_H + ks * 32 + lq * 8];
    v8s b = *(const v8s*)(Wht + lrow * 128 + ks * 32 + lq * 8);
    acc = __builtin_amdgcn_mfma_f32_16x16x32_bf16(a, b, acc, 0, 0, 0);
  }
  float bv = bh[lrow];
#pragma unroll
  for (int r = 0; r < 4; ++r)
    Ps[wave * 16 + lq * 4 + r][lrow] = acc[r] + bv;
  __syncthreads();

  if (t < 64) {
    int row = m0 + t;
    if (row < M) {
      float t_[5], i_[4], mb[3];
#pragma unroll
      for (int o = 0; o < 5; ++o) t_[o] = Ps[t][o];
#pragma unroll
      for (int o = 0; o < 4; ++o) i_[o] = Ps[t][5 + o];
#pragma unroll
      for (int o = 0; o < 3; ++o) mb[o] = Ps[t][9 + o];
      float tp[5];
#pragma unroll
      for (int o = 0; o < 5; ++o) tp[o] = 1.f / (1.f + __expf(-t_[o]));
      float mx = fmaxf(fmaxf(i_[0], i_[1]), fmaxf(i_[2], i_[3]));
      float ex[4], es = 0.f;
#pragma unroll
      for (int o = 0; o < 4; ++o) { ex[o] = __expf(i_[o] - mx); es += ex[o]; }
      float inv_es = 1.f / es;
      float ml[3];
#pragma unroll
      for (int o = 0; o < 3; ++o) {
        float v = mb[o];
#pragma unroll
        for (int j = 0; j < 5; ++j) v += tp[j] * Wm[(128 + j) * 3 + o];
#pragma unroll
        for (int j = 0; j < 4; ++j) v += (ex[j] * inv_es) * Wm[(133 + j) * 3 + o];
        ml[o] = v;
      }
#pragma unroll
      for (int o = 0; o < 5; ++o) out_t[(size_t)row * 5 + o] = t_[o];
#pragma unroll
      for (int o = 0; o < 4; ++o) out_i[(size_t)row * 4 + o] = i_[o];
#pragma unroll
      for (int o = 0; o < 3; ++o) out_m[(size_t)row * 3 + o] = ml[o];
    }
  }
}

// ------------------------------------------------------------------
extern "C" void kernel_launch(void* const* d_in, const int* in_sizes, int n_in,
                              void* d_out, int out_size, void* d_ws, size_t ws_size,
                              hipStream_t stream) {
  const float* x_comment = (const float*)d_in[0];
  const float* x_topic   = (const float*)d_in[1];
  const float* x_claim   = (const float*)d_in[2];
  const float* c1s_Wl = (const float*)d_in[3];
  const float* c1s_bl = (const float*)d_in[4];
  const float* c1s_Wr = (const float*)d_in[5];
  const float* c1a_Wl = (const float*)d_in[6];
  const float* c1a_bl = (const float*)d_in[7];
  const float* c1a_Wr = (const float*)d_in[8];
  const float* c1t_Wl = (const float*)d_in[9];
  const float* c1t_bl = (const float*)d_in[10];
  const float* c1t_Wr = (const float*)d_in[11];
  const float* c2s_Wl = (const float*)d_in[12];
  const float* c2s_bl = (const float*)d_in[13];
  const float* c2s_Wr = (const float*)d_in[14];
  const float* c2a_Wl = (const float*)d_in[15];
  const float* c2a_bl = (const float*)d_in[16];
  const float* c2a_Wr = (const float*)d_in[17];
  const float* c2t_Wl = (const float*)d_in[18];
  const float* c2t_bl = (const float*)d_in[19];
  const float* c2t_Wr = (const float*)d_in[20];
  const float* Wt = (const float*)d_in[21];
  const float* bt = (const float*)d_in[22];
  const float* Wi = (const float*)d_in[23];
  const float* bi = (const float*)d_in[24];
  const float* Wm = (const float*)d_in[25];
  const float* bm = (const float*)d_in[26];
  const int* ei_sim = (const int*)d_in[27];
  const int* ei_ab  = (const int*)d_in[28];
  const int* ei_tg  = (const int*)d_in[29];

  const int E_sim = in_sizes[27] / 2;
  const int E_ab  = in_sizes[28] / 2;
  const int E_tg  = in_sizes[29] / 2;
  const int N_T = in_sizes[1] / 128;
  const int N_CL = in_sizes[2] / 128;

  float* ws = (float*)d_ws;
  unsigned short* h1 = (unsigned short*)ws;                // 100000*128 bf16
  unsigned short* y_s = (unsigned short*)(ws + 12800000);  // 100000*128 bf16 (arena head)
  unsigned short* y_a = (unsigned short*)(ws + 19200000);  // 5000*128 bf16 (arena row 100000)
  unsigned short* y_t = (unsigned short*)(ws + 19520000);  // 20000*128 bf16 (arena row 105000)
  int*   cnt    = (int*)(ws + 20800000);                   // 3*N_C (also fill)
  float* inv    = ws + 21100000;                           // 3*N_C
  int*   base3  = (int*)(ws + 21400000);                   // 3*N_C placement bases
  unsigned int* srcm = (unsigned int*)(ws + 21700016);     // E_sim+E_ab+E_tg merged
  int*   part   = (int*)(ws + 22900016);                   // 128
  float* b1s    = ws + 22900416;
  float* b2s    = ws + 22900544;
  unsigned short* Bt_c1s = (unsigned short*)(ws + 22900672);  // 128x256
  unsigned short* Bt_W1s = Bt_c1s + 32768;                    // 128x256
  unsigned short* Bt_c1a = Bt_W1s + 32768;                    // 128x128
  unsigned short* Bt_c1t = Bt_c1a + 16384;
  unsigned short* Bt_c2s = Bt_c1t + 16384;
  unsigned short* Bt_W2s = Bt_c2s + 16384;
  unsigned short* Bt_c2a = Bt_W2s + 16384;
  unsigned short* Bt_c2t = Bt_c2a + 16384;
  int*   rs_m   = (int*)(ws + 23000000);                   // N_C+1 merged row-ptr
  unsigned short* Wht = (unsigned short*)(ws + 24600000);     // 16x128 bf16
  float* bh     = ws + 24601100;                              // 16

  const int nbS = (N_C + SCAN_CHUNK - 1) / SCAN_CHUNK;
  const int ebx = (E_sim + 255) / 256;
  const int nbC = (N_C + 127) / 128;
  const int nbT = (N_T + 127) / 128;
  const int nbCl = (N_CL + 127) / 128;
  const size_t lds_bytes = (3 * 4096 + 2 * 8192) * sizeof(unsigned short);  // 57344

  // ---- weight prep ----
  prep_weights<<<dim3(128, 10), 256, 0, stream>>>(
      c1s_Wl, c1s_Wr, c1a_Wr, c1t_Wr, c1a_Wl, c1t_Wl,
      c2s_Wl, c2s_Wr, c2a_Wr, c2t_Wr, c2a_Wl, c2t_Wl,
      c1s_bl, c1a_bl, c1t_bl, c2s_bl, c2a_bl, c2t_bl,
      Wt, bt, Wi, bi, Wm, bm,
      Bt_c1s, Bt_W1s, Bt_c1a, Bt_c1t, Bt_c2s, Bt_W2s, Bt_c2a, Bt_c2t,
      Wht, b1s, b2s, bh);

  // ---- degree histogram + merged CSR build ----
  hipMemsetAsync(cnt, 0, 3 * N_C * sizeof(int), stream);
  count3_kernel<<<dim3(ebx, 3), 256, 0, stream>>>(ei_sim, E_sim, ei_ab, E_ab, ei_tg, E_tg, cnt);
  scan_phaseA<<<dim3(nbS, 1), 256, 0, stream>>>(cnt, part, inv, N_C);
  scan_phaseB<<<dim3(1, 1), 256, 0, stream>>>(part, nbS);
  scan_phaseC<<<dim3(nbS, 1), 256, 0, stream>>>(cnt, part, rs_m, base3, N_C);
  set_totals<<<1, 64, 0, stream>>>(rs_m, E_sim + E_ab + E_tg, N_C);
  place3_kernel<<<dim3(ebx, 3), 256, 0, stream>>>(
      ei_sim, E_sim, ei_ab, E_ab, ei_tg, E_tg, base3, cnt, srcm,
      N_C, N_C + N_T, N_C);

  // ---------------- layer 1 (fused 3 GEMMs) ----------------
  layer1_kernel<<<nbC + nbT + nbCl, 256, lds_bytes, stream>>>(
      x_comment, N_C, Bt_c1s, Bt_W1s, y_s, h1, b1s,
      x_topic, N_T, Bt_c1a, y_a,
      x_claim, N_CL, Bt_c1t, y_t, nbC, nbT);

  gather_kernel<<<(N_C + 3) / 4, 256, 0, stream>>>(
      y_s, rs_m, srcm, inv, h1, N_C);

  // ---------------- layer 2 (fused 3 GEMMs, h in-place bf16) --------
  layer2_kernel<<<nbC + nbT + nbCl, 256, lds_bytes, stream>>>(
      h1, N_C, Bt_c2s, Bt_W2s, y_s, b2s,
      x_topic, N_T, Bt_c2a, y_a,
      x_claim, N_CL, Bt_c2t, y_t, nbC, nbT);

  gather_kernel<<<(N_C + 3) / 4, 256, 0, stream>>>(
      y_s, rs_m, srcm, inv, h1, N_C);

  // ---------------- heads (fully fused) ----------------
  float* out = (float*)d_out;
  heads_kernel<<<(N_C + 63) / 64, 256, 0, stream>>>(
      h1, N_C, Wht, bh, Wm,
      out, out + (size_t)N_C * 5, out + (size_t)N_C * 9);
}

// Round 5
// 494.405 us; speedup vs baseline: 1.0952x; 1.0120x over previous
//
#include <hip/hip_runtime.h>
#include <math.h>

#define N_C 100000
#define HD 128
#define SCAN_CHUNK 1024

typedef short v8s __attribute__((ext_vector_type(8)));
typedef float v4f __attribute__((ext_vector_type(4)));
typedef __attribute__((address_space(1))) const void gas_t;
typedef __attribute__((address_space(3))) void las_t;

__device__ __forceinline__ unsigned short f2bf(float f) {
  unsigned int u = __float_as_uint(f);
  u += 0x7fffu + ((u >> 16) & 1u);
  return (unsigned short)(u >> 16);
}

// exact relu on two packed bf16 halves (negative & -0 -> +0)
__device__ __forceinline__ unsigned int relu2(unsigned int u) {
  unsigned int m = ((u & 0x80008000u) >> 15) * 0xFFFFu;
  return u & ~m;
}

// counted-wait helper: n is compile-time-foldable at every call site
__device__ __forceinline__ void vmcnt_sel(int n) {
  if (n >= 8)      asm volatile("s_waitcnt vmcnt(8)" ::: "memory");
  else if (n == 6) asm volatile("s_waitcnt vmcnt(6)" ::: "memory");
  else if (n == 5) asm volatile("s_waitcnt vmcnt(5)" ::: "memory");
  else if (n == 4) asm volatile("s_waitcnt vmcnt(4)" ::: "memory");
  else if (n == 3) asm volatile("s_waitcnt vmcnt(3)" ::: "memory");
  else if (n == 2) asm volatile("s_waitcnt vmcnt(2)" ::: "memory");
  else if (n == 1) asm volatile("s_waitcnt vmcnt(1)" ::: "memory");
  else             asm volatile("s_waitcnt vmcnt(0)" ::: "memory");
}
__device__ __forceinline__ void s_lgkm0() { asm volatile("s_waitcnt lgkmcnt(0)" ::: "memory"); }
__device__ __forceinline__ void s_bar() { __builtin_amdgcn_s_barrier(); }

// ------------------------------------------------------------------
// merged 3-phase exclusive scan over c0+c1+c2; phaseA emits inv (all 3
// segs), phaseC zeroes cnt (fill reuse) and emits merged row-ptr rs_m
// plus per-(seg,row) placement bases.
// ------------------------------------------------------------------
__global__ __launch_bounds__(256) void scan_phaseA(const int* __restrict__ cnt,
                                                   int* __restrict__ partial,
                                                   float* __restrict__ inv, int n) {
  __shared__ int sdata[256];
  int base_i = blockIdx.x * SCAN_CHUNK + threadIdx.x * 4;
  int s = 0;
#pragma unroll
  for (int j = 0; j < 4; ++j) {
    int idx = base_i + j;
    if (idx < n) {
      int c0 = cnt[idx], c1 = cnt[n + idx], c2 = cnt[2 * n + idx];
      s += c0 + c1 + c2;
      inv[idx] = 1.0f / fmaxf((float)c0, 1.0f);
      inv[n + idx] = 1.0f / fmaxf((float)c1, 1.0f);
      inv[2 * n + idx] = 1.0f / fmaxf((float)c2, 1.0f);
    }
  }
  sdata[threadIdx.x] = s;
  __syncthreads();
  for (int off = 128; off > 0; off >>= 1) {
    if (threadIdx.x < off) sdata[threadIdx.x] += sdata[threadIdx.x + off];
    __syncthreads();
  }
  if (threadIdx.x == 0) partial[blockIdx.x] = sdata[0];
}

__global__ __launch_bounds__(256) void scan_phaseB(int* __restrict__ partial, int nb) {
  __shared__ int sdata[256];
  int t = threadIdx.x;
  int v = (t < nb) ? partial[t] : 0;
  sdata[t] = v;
  __syncthreads();
  for (int off = 1; off < 256; off <<= 1) {
    int x = (t >= off) ? sdata[t - off] : 0;
    __syncthreads();
    sdata[t] += x;
    __syncthreads();
  }
  if (t < nb) partial[t] = sdata[t] - v;
}

__global__ __launch_bounds__(256) void scan_phaseC(int* __restrict__ cnt,
                                                   const int* __restrict__ partial,
                                                   int* __restrict__ rs_m,
                                                   int* __restrict__ base, int n) {
  __shared__ int sdata[256];
  int t = threadIdx.x;
  int base_i = blockIdx.x * SCAN_CHUNK + t * 4;
  int c0[4], c1[4], v[4];
  int s = 0;
#pragma unroll
  for (int j = 0; j < 4; ++j) {
    int idx = base_i + j;
    int a = 0, b = 0, c = 0;
    if (idx < n) {
      a = cnt[idx]; b = cnt[n + idx]; c = cnt[2 * n + idx];
      cnt[idx] = 0; cnt[n + idx] = 0; cnt[2 * n + idx] = 0;  // fill reuse
    }
    c0[j] = a; c1[j] = b;
    v[j] = a + b + c;
    s += v[j];
  }
  sdata[t] = s;
  __syncthreads();
  for (int off = 1; off < 256; off <<= 1) {
    int x = (t >= off) ? sdata[t - off] : 0;
    __syncthreads();
    sdata[t] += x;
    __syncthreads();
  }
  int run = sdata[t] - s + partial[blockIdx.x];
#pragma unroll
  for (int j = 0; j < 4; ++j) {
    int idx = base_i + j;
    if (idx < n) {
      rs_m[idx] = run;
      base[idx] = run;
      base[n + idx] = run + c0[j];
      base[2 * n + idx] = run + c0[j] + c1[j];
    }
    run += v[j];
  }
}

__global__ void set_totals(int* rs_m, int Etot, int n) {
  if (threadIdx.x == 0) rs_m[n] = Etot;
}

// ------------------------------------------------------------------
// fused prep + count kernel: blocks [0, nCB) do the 3-segment degree
// histogram (8 edges/thread, ILP chains); blocks [nCB, nCB+1280) do
// weight transposes+cvt (y=0..7), biases (y=8), head weight (y=9).
// ------------------------------------------------------------------
__global__ __launch_bounds__(256) void prep_count_kernel(
    const float* __restrict__ c1s_Wl, const float* __restrict__ c1s_Wr,
    const float* __restrict__ c1a_Wr, const float* __restrict__ c1t_Wr,
    const float* __restrict__ c1a_Wl, const float* __restrict__ c1t_Wl,
    const float* __restrict__ c2s_Wl, const float* __restrict__ c2s_Wr,
    const float* __restrict__ c2a_Wr, const float* __restrict__ c2t_Wr,
    const float* __restrict__ c2a_Wl, const float* __restrict__ c2t_Wl,
    const float* __restrict__ c1s_bl, const float* __restrict__ c1a_bl,
    const float* __restrict__ c1t_bl, const float* __restrict__ c2s_bl,
    const float* __restrict__ c2a_bl, const float* __restrict__ c2t_bl,
    const float* __restrict__ Wt, const float* __restrict__ bt,
    const float* __restrict__ Wi, const float* __restrict__ bi,
    const float* __restrict__ Wm, const float* __restrict__ bm,
    unsigned short* __restrict__ Bt_c1s, unsigned short* __restrict__ Bt_W1s,
    unsigned short* __restrict__ Bt_c1a, unsigned short* __restrict__ Bt_c1t,
    unsigned short* __restrict__ Bt_c2s, unsigned short* __restrict__ Bt_W2s,
    unsigned short* __restrict__ Bt_c2a, unsigned short* __restrict__ Bt_c2t,
    unsigned short* __restrict__ Wht,
    float* __restrict__ b1s, float* __restrict__ b2s, float* __restrict__ bh,
    const int* __restrict__ ei_s, int Es, const int* __restrict__ ei_a, int Ea,
    const int* __restrict__ ei_t, int Et, int* __restrict__ cnt, int nCB) {
  int b = blockIdx.x;
  if (b < nCB) {
    int nb0 = (Es + 2047) >> 11, nb1 = (Ea + 2047) >> 11;
    const int* ei; int E; int off; int e0;
    if (b < nb0)            { ei = ei_s; E = Es; off = 0;         e0 = b << 11; }
    else if (b < nb0 + nb1) { ei = ei_a; E = Ea; off = N_C;       e0 = (b - nb0) << 11; }
    else                    { ei = ei_t; E = Et; off = 2 * N_C;   e0 = (b - nb0 - nb1) << 11; }
    int tt = threadIdx.x;
#pragma unroll
    for (int j = 0; j < 8; ++j) {
      int idx = e0 + j * 256 + tt;
      if (idx < E) atomicAdd(&cnt[off + ei[E + idx]], 1);
    }
    return;
  }
  int q = b - nCB;
  int y = q >> 7;
  int xb = q & 127;
  int idx = xb * 256 + threadIdx.x;
  if (y == 8) {
    if (xb == 0) {
      int t = threadIdx.x;
      if (t < 128) b1s[t] = c1s_bl[t] + c1a_bl[t] + c1t_bl[t];
      else b2s[t - 128] = c2s_bl[t - 128] + c2a_bl[t - 128] + c2t_bl[t - 128];
    } else if (xb == 1) {
      int t = threadIdx.x;
      if (t < 16) {
        float v = 0.f;
        if (t < 5) v = bt[t];
        else if (t < 9) v = bi[t - 5];
        else if (t < 12) v = bm[t - 9];
        bh[t] = v;
      }
    }
    return;
  }
  if (y == 9) {
    if (idx < 16 * 128) {
      int o = idx >> 7, k = idx & 127;
      float v = 0.f;
      if (o < 5) v = Wt[k * 5 + o];
      else if (o < 9) v = Wi[k * 4 + (o - 5)];
      else if (o < 12) v = Wm[k * 3 + (o - 9)];
      Wht[o * 128 + k] = f2bf(v);
    }
    return;
  }
  int K = (y < 2) ? 256 : 128;
  if (idx >= K * 128) return;
  int k = idx >> 7, n = idx & 127;
  float v;
  unsigned short* out;
  switch (y) {
    case 0: v = c1s_Wl[idx]; out = Bt_c1s; break;
    case 1: v = c1s_Wr[idx] + c1a_Wr[idx] + c1t_Wr[idx]; out = Bt_W1s; break;
    case 2: v = c1a_Wl[idx]; out = Bt_c1a; break;
    case 3: v = c1t_Wl[idx]; out = Bt_c1t; break;
    case 4: v = c2s_Wl[idx]; out = Bt_c2s; break;
    case 5: v = c2s_Wr[idx] + c2a_Wr[idx] + c2t_Wr[idx]; out = Bt_W2s; break;
    case 6: v = c2a_Wl[idx]; out = Bt_c2a; break;
    default: v = c2t_Wl[idx]; out = Bt_c2t; break;
  }
  out[n * K + k] = f2bf(v);
}

// ------------------------------------------------------------------
// merged placement (8 edges/thread, ILP chains):
//   srcm[p] = (src + arena_row_offset) | (seg << 28)
// ------------------------------------------------------------------
__device__ __forceinline__ void place_body(
    int pb, const int* __restrict__ ei_s, int Es,
    const int* __restrict__ ei_a, int Ea, const int* __restrict__ ei_t, int Et,
    const int* __restrict__ base, int* __restrict__ fill,
    unsigned int* __restrict__ srcm, int offA, int offT, int n) {
  int nb0 = (Es + 2047) >> 11, nb1 = (Ea + 2047) >> 11;
  const int* ei; int E; unsigned roff; int y; int e0;
  if (pb < nb0)            { ei = ei_s; E = Es; roff = 0u;             y = 0; e0 = pb << 11; }
  else if (pb < nb0 + nb1) { ei = ei_a; E = Ea; roff = (unsigned)offA; y = 1; e0 = (pb - nb0) << 11; }
  else                     { ei = ei_t; E = Et; roff = (unsigned)offT; y = 2; e0 = (pb - nb0 - nb1) << 11; }
  int tt = threadIdx.x;
  int d[8], s[8];
#pragma unroll
  for (int j = 0; j < 8; ++j) {
    int idx = e0 + j * 256 + tt;
    bool v = idx < E;
    d[j] = v ? ei[E + idx] : -1;
    s[j] = v ? ei[idx] : 0;
  }
#pragma unroll
  for (int j = 0; j < 8; ++j) {
    if (d[j] >= 0) {
      int p = base[y * n + d[j]] + atomicAdd(&fill[y * n + d[j]], 1);
      srcm[p] = ((unsigned)s[j] + roff) | ((unsigned)y << 28);
    }
  }
}

// ------------------------------------------------------------------
// GEMM body, counted-vmcnt pipeline, slim 64x32 wave-tile:
//   C0(bf16) = A@B0 [, C1(bf16) = A@B1 + bias1]
// M-tile 128, N-tile BN (64: 256thr/4w, 2Mx2N; 128: 512thr/8w, 2Mx4N),
// BK=32, mfma 16x16x32 bf16. acc dual = 16 v4f (64 AGPR).
// A: HBM stream, depth-2. bf16 -> global_load_lds (3 bufs); fp32 ->
//   2 reg-sets loaded 2 ahead, cvt+ds_write 1 ahead.
// B: L2-resident panel, depth-1 via global_load_lds (2 bufs).
// One s_barrier per K-step; counted vmcnt: top wait retires B(kt)
// leaving A(kt+1..2) in flight; vmcnt(0) only at the last step.
// ALL staging loads use CLAMPED row addresses and always issue, so the
// per-wave outstanding-vmem count exactly matches the derived waits for
// every wave (incl. all-OOB tail waves). OOB rows load garbage that
// only reaches never-stored C rows (epilogue guards gr < M).
// Layer-2 in-place (A=C1=h1, BN=128): block reads only its own rows,
// all A loads drained (final vmcnt(0) + barrier) before epilogue.
// ------------------------------------------------------------------
template <int KD, bool DUAL, bool ABF16, int BN, int TPB>
__device__ __forceinline__ void gemm_body(
    int bx, int nh, unsigned short* smem, const void* Av, int M,
    const unsigned short* __restrict__ B0t, const unsigned short* __restrict__ B1t,
    unsigned short* __restrict__ C0, unsigned short* C1,
    const float* __restrict__ bias1) {
  constexpr int NT = KD / 32;
  constexpr int W = TPB / 64;                       // waves per block
  constexpr int nA = ABF16 ? (8 / W) : (TPB == 256 ? 4 : 2);  // vmem ops/thread per A tile
  constexpr int nB = DUAL ? 2 : 1;                  // vmem ops/thread per B tile
  constexpr int BS = BN * 64;                       // B buffer stride (shorts, dual-size)
  const int t = threadIdx.x;
  const int wave = t >> 6, lane = t & 63;
  const int wm = (wave & 1) * 64;
  const int wn = (wave >> 1) * 32;
  const int m0 = bx * 128;
  const int n0 = nh * BN;
  const int lrow = lane & 15, lq = lane >> 4;
  // swizzled fragment col offset (shorts): slot = lq ^ ((row>>1)&3)
  const int fg = (lq ^ ((lrow >> 1) & 3)) * 8;
  // gload_lds staging lane constants: 1KB chunk = 16 rows x 64B
  const int sr = lane >> 2;                         // row within chunk
  const int sg = (lane & 3) ^ ((lane >> 3) & 3);    // swizzled source col-group

  const float* Af = (const float*)Av;
  const unsigned short* Ab_g = (const unsigned short*)Av;

  auto Abuf = [&](int i) { return smem + (i % 3) * 4096; };
  auto Bbuf = [&](int i) { return smem + 12288 + (i & 1) * BS; };

  v4f acc0[4][2];
  v4f acc1[DUAL ? 4 : 1][DUAL ? 2 : 1];
#pragma unroll
  for (int i = 0; i < 4; ++i)
#pragma unroll
    for (int j = 0; j < 2; ++j) acc0[i][j] = (v4f)(0.f);
  if constexpr (DUAL) {
#pragma unroll
    for (int i = 0; i < 4; ++i)
#pragma unroll
      for (int j = 0; j < 2; ++j) acc1[i][j] = (v4f)(0.f);
  }

  float4 ar0[TPB == 256 ? 4 : 2], ar1[TPB == 256 ? 4 : 2];  // fp32-A staging

  auto stageB = [&](unsigned short* ldsB, int k0) {
    // B tile: BN rows x 32 shorts; BN/16 == W chunks, chunk = wave
    const unsigned short* s0 = B0t + (size_t)(n0 + wave * 16 + sr) * KD + k0 + sg * 8;
    __builtin_amdgcn_global_load_lds((gas_t*)s0, (las_t*)(ldsB + wave * 512), 16, 0, 0);
    if constexpr (DUAL) {
      const unsigned short* s1 = B1t + (size_t)(n0 + wave * 16 + sr) * KD + k0 + sg * 8;
      __builtin_amdgcn_global_load_lds((gas_t*)s1, (las_t*)(ldsB + BN * 32 + wave * 512), 16, 0, 0);
    }
  };
  auto stageA_dma = [&](unsigned short* lds, int k0) {
#pragma unroll
    for (int j = 0; j < 8 / W; ++j) {
      int cidx = j * W + wave;
      int gr = m0 + cidx * 16 + sr;
      if (gr >= M) gr = M - 1;  // clamp: OOB rows read garbage, never written back
      const unsigned short* src = Ab_g + (size_t)gr * KD + k0 + sg * 8;
      __builtin_amdgcn_global_load_lds((gas_t*)src, (las_t*)(lds + cidx * 512), 16, 0, 0);
    }
  };
  auto loadAf = [&](int k0, float4* ar) {
    // clamped row address; loads ALWAYS issued (exact vmcnt accounting)
    if constexpr (TPB == 256) {
      int r = t >> 1, h = t & 1;
      int gr = m0 + r; if (gr >= M) gr = M - 1;
      const float* src = Af + (size_t)gr * KD + k0 + h * 16;
#pragma unroll
      for (int j = 0; j < 4; ++j) ar[j] = *(const float4*)(src + j * 4);
    } else {
      int r = t >> 2, q = t & 3;
      int gr = m0 + r; if (gr >= M) gr = M - 1;
      const float* src = Af + (size_t)gr * KD + k0 + q * 8;
      ar[0] = *(const float4*)(src);
      ar[1] = *(const float4*)(src + 4);
    }
  };
  auto writeAf = [&](const float4* ar, unsigned short* lds) {
    auto pk = [](float a, float b) {
      return (unsigned int)f2bf(a) | ((unsigned int)f2bf(b) << 16);
    };
    if constexpr (TPB == 256) {
      int r = t >> 1, h = t & 1, sw = (r >> 1) & 3;
      uint4 w0 = make_uint4(pk(ar[0].x, ar[0].y), pk(ar[0].z, ar[0].w),
                            pk(ar[1].x, ar[1].y), pk(ar[1].z, ar[1].w));
      uint4 w1 = make_uint4(pk(ar[2].x, ar[2].y), pk(ar[2].z, ar[2].w),
                            pk(ar[3].x, ar[3].y), pk(ar[3].z, ar[3].w));
      *(uint4*)&lds[r * 32 + ((2 * h) ^ sw) * 8] = w0;
      *(uint4*)&lds[r * 32 + ((2 * h + 1) ^ sw) * 8] = w1;
    } else {
      int r = t >> 2, q = t & 3, sw = (r >> 1) & 3;
      uint4 w0 = make_uint4(pk(ar[0].x, ar[0].y), pk(ar[0].z, ar[0].w),
                            pk(ar[1].x, ar[1].y), pk(ar[1].z, ar[1].w));
      *(uint4*)&lds[r * 32 + (q ^ sw) * 8] = w0;
    }
  };

  // ---- prologue: queue order A(0), B(0), A(1) ----
  if constexpr (ABF16) {
    stageA_dma(Abuf(0), 0);
    stageB(Bbuf(0), 0);
    stageA_dma(Abuf(1), 32);
  } else {
    loadAf(0, ar0);
    stageB(Bbuf(0), 0);
    loadAf(32, ar1);
    vmcnt_sel(nB + nA);  // retire A(0) regs; B(0)+A(1) stay in flight
    writeAf(ar0, Abuf(0));
    s_lgkm0();
  }

#pragma unroll
  for (int kt = 0; kt < NT; ++kt) {
    // top wait: retire through B(kt); A(kt+1) [+A(kt+2)] stay in flight
    vmcnt_sel((kt + 1 < NT) ? nA : 0);
    s_bar();  // tile kt fully in LDS; all waves done reading old bufs

    if (kt + 1 < NT) stageB(Bbuf(kt + 1), (kt + 1) * 32);
    if (kt + 2 < NT) {
      if constexpr (ABF16) stageA_dma(Abuf(kt + 2), (kt + 2) * 32);
      else loadAf((kt + 2) * 32, ((kt & 1) == 0) ? ar0 : ar1);
    }

    unsigned short* cAs = Abuf(kt);
    unsigned short* cB = Bbuf(kt);
    v8s af[4];
#pragma unroll
    for (int mt = 0; mt < 4; ++mt)
      af[mt] = *(const v8s*)&cAs[(wm + mt * 16 + lrow) * 32 + fg];
    __builtin_amdgcn_s_setprio(1);
#pragma unroll
    for (int cb = 0; cb < 2; ++cb) {
      v8s b0 = *(const v8s*)&cB[(wn + cb * 16 + lrow) * 32 + fg];
#pragma unroll
      for (int mt = 0; mt < 4; ++mt)
        acc0[mt][cb] = __builtin_amdgcn_mfma_f32_16x16x32_bf16(af[mt], b0, acc0[mt][cb], 0, 0, 0);
      if constexpr (DUAL) {
        v8s b1 = *(const v8s*)&cB[BN * 32 + (wn + cb * 16 + lrow) * 32 + fg];
#pragma unroll
        for (int mt = 0; mt < 4; ++mt)
          acc1[mt][cb] = __builtin_amdgcn_mfma_f32_16x16x32_bf16(af[mt], b1, acc1[mt][cb], 0, 0, 0);
      }
    }
    __builtin_amdgcn_s_setprio(0);

    if constexpr (!ABF16) {
      if (kt + 1 < NT) {
        // retire A(kt+1) reg-loads; B(kt+1) [+A(kt+2)] stay in flight
        vmcnt_sel(nB + ((kt + 2 < NT) ? nA : 0));
        writeAf(((kt & 1) == 0) ? ar1 : ar0, Abuf(kt + 1));
        s_lgkm0();  // ds_writes visible before next barrier
      }
    }
  }

  // ---- epilogue (all loads drained by final vmcnt(0)) ----
  float bv[2] = {0.f, 0.f};
  if constexpr (DUAL) {
#pragma unroll
    for (int cb = 0; cb < 2; ++cb) bv[cb] = bias1[n0 + wn + cb * 16 + lrow];
  }
#pragma unroll
  for (int mt = 0; mt < 4; ++mt) {
#pragma unroll
    for (int r = 0; r < 4; ++r) {
      int gr = m0 + wm + mt * 16 + lq * 4 + r;
      if (gr < M) {
#pragma unroll
        for (int cb = 0; cb < 2; ++cb) {
          int gc = n0 + wn + cb * 16 + lrow;
          C0[(size_t)gr * 128 + gc] = f2bf(acc0[mt][cb][r]);
          if constexpr (DUAL) C1[(size_t)gr * 128 + gc] = f2bf(acc1[mt][cb][r] + bv[cb]);
        }
      }
    }
  }
}

// ------------------------------------------------------------------
// layer1: 256-thr blocks, tile 128x64 (col-split), fp32 A, 12 waves/CU
// target; place3 blocks fused behind the GEMM blocks (independent).
// dynamic LDS = (3*4096 + 2*4096) shorts = 40960 bytes
// ------------------------------------------------------------------
__global__ __launch_bounds__(256, 3) void layer1_kernel(
    const float* __restrict__ xc, int Mc,
    const unsigned short* __restrict__ Bc0, const unsigned short* __restrict__ Bc1,
    unsigned short* __restrict__ y_s, unsigned short* __restrict__ h1,
    const float* __restrict__ b1s,
    const float* __restrict__ xt, int Mt, const unsigned short* __restrict__ Bt_,
    unsigned short* __restrict__ y_a,
    const float* __restrict__ xcl, int Mcl, const unsigned short* __restrict__ Bcl,
    unsigned short* __restrict__ y_t, int nbC, int nbT, int nbCl,
    const int* __restrict__ ei_s, int Es, const int* __restrict__ ei_a, int Ea,
    const int* __restrict__ ei_t, int Et,
    const int* __restrict__ base3, int* __restrict__ fill,
    unsigned int* __restrict__ srcm, int offA, int offT, int n) {
  extern __shared__ unsigned short smem[];
  int b = blockIdx.x;
  if (b < 2 * nbC) {
    gemm_body<256, true, false, 64, 256>(b >> 1, b & 1, smem, xc, Mc, Bc0, Bc1, y_s, h1, b1s);
  } else if (b < 2 * (nbC + nbT)) {
    int q = b - 2 * nbC;
    gemm_body<128, false, false, 64, 256>(q >> 1, q & 1, smem, xt, Mt, Bt_, nullptr, y_a, nullptr, nullptr);
  } else if (b < 2 * (nbC + nbT + nbCl)) {
    int q = b - 2 * (nbC + nbT);
    gemm_body<128, false, false, 64, 256>(q >> 1, q & 1, smem, xcl, Mcl, Bcl, nullptr, y_t, nullptr, nullptr);
  } else {
    place_body(b - 2 * (nbC + nbT + nbCl), ei_s, Es, ei_a, Ea, ei_t, Et,
               base3, fill, srcm, offA, offT, n);
  }
}

// ------------------------------------------------------------------
// layer2: 512-thr blocks, tile 128x128, all-DMA bf16 comment path,
// 16 waves/CU target. h in-place (A=C1=h1, own rows only).
// dynamic LDS = (3*4096 + 2*8192) shorts = 57344 bytes
// ------------------------------------------------------------------
__global__ __launch_bounds__(512, 4) void layer2_kernel(
    unsigned short* h1, int Mc,
    const unsigned short* __restrict__ Bc0, const unsigned short* __restrict__ Bc1,
    unsigned short* __restrict__ y_s, const float* __restrict__ b2s,
    const float* __restrict__ xt, int Mt, const unsigned short* __restrict__ Bt_,
    unsigned short* __restrict__ y_a,
    const float* __restrict__ xcl, int Mcl, const unsigned short* __restrict__ Bcl,
    unsigned short* __restrict__ y_t, int nbC, int nbT) {
  extern __shared__ unsigned short smem[];
  int b = blockIdx.x;
  if (b < nbC)
    gemm_body<128, true, true, 128, 512>(b, 0, smem, h1, Mc, Bc0, Bc1, y_s, h1, b2s);
  else if (b < nbC + nbT)
    gemm_body<128, false, false, 128, 512>(b - nbC, 0, smem, xt, Mt, Bt_, nullptr, y_a, nullptr, nullptr);
  else
    gemm_body<128, false, false, 128, 512>(b - nbC - nbT, 0, smem, xcl, Mcl, Bcl, nullptr, y_t, nullptr, nullptr);
}

// ------------------------------------------------------------------
// fused CSR gather over the MERGED per-row edge list. One wave per row,
// quarter-wave strides the row's edges; 2-deep software pipeline;
// per-edge scale (seg tag in bits 28+); h RMW applies relu.
// ------------------------------------------------------------------
__global__ __launch_bounds__(256) void gather_kernel(
    const unsigned short* __restrict__ yall,
    const int* __restrict__ rs_m, const unsigned int* __restrict__ srcm,
    const float* __restrict__ inv, unsigned short* h, int M) {
  int row = blockIdx.x * 4 + (threadIdx.x >> 6);
  if (row >= M) return;
  const int lane = threadIdx.x & 63;
  const int q = lane >> 4;
  const int col = (lane & 15) * 8;

  int mb = rs_m[row], me = rs_m[row + 1];
  float sc0 = inv[row], sc1 = inv[M + row], sc2 = inv[2 * M + row];

  uint4 hv = *(const uint4*)(h + (size_t)row * HD + col);

  float a0 = 0.f, a1 = 0.f, a2 = 0.f, a3 = 0.f;
  float a4 = 0.f, a5 = 0.f, a6 = 0.f, a7 = 0.f;

  if (me > mb) {
    const int last = me - 1;
    const int ntrip = (me - mb + 3) >> 2;  // wave-uniform
    int i = mb + q;
    unsigned ec = srcm[min(i, last)];
    uint4 vc = *(const uint4*)(yall + (size_t)(ec & 0x0FFFFFFFu) * HD + col);
    unsigned en = (ntrip > 1) ? srcm[min(i + 4, last)] : ec;
    for (int j = 0; j < ntrip; ++j) {
      unsigned ecur = ec;
      uint4 v = vc;
      if (j + 1 < ntrip) {
        vc = *(const uint4*)(yall + (size_t)(en & 0x0FFFFFFFu) * HD + col);
        ec = en;
        if (j + 2 < ntrip) en = srcm[min(i + 8, last)];
      }
      int sgm = ecur >> 28;
      float s = (i < me) ? (sgm == 0 ? sc0 : (sgm == 1 ? sc1 : sc2)) : 0.f;
      a0 = fmaf(__uint_as_float(v.x << 16), s, a0);
      a1 = fmaf(__uint_as_float(v.x & 0xffff0000u), s, a1);
      a2 = fmaf(__uint_as_float(v.y << 16), s, a2);
      a3 = fmaf(__uint_as_float(v.y & 0xffff0000u), s, a3);
      a4 = fmaf(__uint_as_float(v.z << 16), s, a4);
      a5 = fmaf(__uint_as_float(v.z & 0xffff0000u), s, a5);
      a6 = fmaf(__uint_as_float(v.w << 16), s, a6);
      a7 = fmaf(__uint_as_float(v.w & 0xffff0000u), s, a7);
      i += 4;
    }
  }

  a0 += __shfl_xor(a0, 16); a0 += __shfl_xor(a0, 32);
  a1 += __shfl_xor(a1, 16); a1 += __shfl_xor(a1, 32);
  a2 += __shfl_xor(a2, 16); a2 += __shfl_xor(a2, 32);
  a3 += __shfl_xor(a3, 16); a3 += __shfl_xor(a3, 32);
  a4 += __shfl_xor(a4, 16); a4 += __shfl_xor(a4, 32);
  a5 += __shfl_xor(a5, 16); a5 += __shfl_xor(a5, 32);
  a6 += __shfl_xor(a6, 16); a6 += __shfl_xor(a6, 32);
  a7 += __shfl_xor(a7, 16); a7 += __shfl_xor(a7, 32);

  if (q == 0) {
    auto upd = [&](unsigned int u, float x0, float x1) {
      float lo = fmaxf(__uint_as_float(u << 16) + x0, 0.f);
      float hi = fmaxf(__uint_as_float(u & 0xffff0000u) + x1, 0.f);
      return (unsigned int)f2bf(lo) | ((unsigned int)f2bf(hi) << 16);
    };
    hv.x = upd(hv.x, a0, a1);
    hv.y = upd(hv.y, a2, a3);
    hv.z = upd(hv.z, a4, a5);
    hv.w = upd(hv.w, a6, a7);
    *(uint4*)(h + (size_t)row * HD + col) = hv;
  }
}

// ------------------------------------------------------------------
// fused heads: P = relu(h2)@Wht^T + bh (MFMA) -> LDS -> epilogue
// ------------------------------------------------------------------
__global__ __launch_bounds__(256, 4) void heads_kernel(
    const unsigned short* __restrict__ h2b, int M,
    const unsigned short* __restrict__ Wht, const float* __restrict__ bh,
    const float* __restrict__ Wm,
    float* __restrict__ out_t, float* __restrict__ out_i,
    float* __restrict__ out_m) {
  constexpr int AST_H = 136;
  __shared__ unsigned short As[64 * AST_H];
  __shared__ float Ps[64][17];
  const int t = threadIdx.x;
  const int wave = t >> 6, lane = t & 63;
  const int m0 = blockIdx.x * 64;
  const int lrow = lane & 15, lq = lane >> 4;

#pragma unroll
  for (int j = 0; j < 4; ++j) {
    int idx = j * 256 + t;
    int row = idx >> 4;
    int c8 = idx & 15;
    int gr = m0 + row;
    uint4 v = make_uint4(0, 0, 0, 0);
    if (gr < M) v = *(const uint4*)(h2b + (size_t)gr * 128 + c8 * 8);
    v.x = relu2(v.x); v.y = relu2(v.y); v.z = relu2(v.z); v.w = relu2(v.w);
    *(uint4*)&As[row * AST_H + c8 * 8] = v;
  }
  __syncthreads();

  v4f acc = (v4f)(0.f);
#pragma unroll
  for (int ks = 0; ks < 4; ++ks) {
    v8s a = *(const v8s*)&As[(wave * 16 + lrow) * AST_H + ks * 32 + lq * 8];
    v8s b = *(const v8s*)(Wht + lrow * 128 + ks * 32 + lq * 8);
    acc = __builtin_amdgcn_mfma_f32_16x16x32_bf16(a, b, acc, 0, 0, 0);
  }
  float bv = bh[lrow];
#pragma unroll
  for (int r = 0; r < 4; ++r)
    Ps[wave * 16 + lq * 4 + r][lrow] = acc[r] + bv;
  __syncthreads();

  if (t < 64) {
    int row = m0 + t;
    if (row < M) {
      float t_[5], i_[4], mb[3];
#pragma unroll
      for (int o = 0; o < 5; ++o) t_[o] = Ps[t][o];
#pragma unroll
      for (int o = 0; o < 4; ++o) i_[o] = Ps[t][5 + o];
#pragma unroll
      for (int o = 0; o < 3; ++o) mb[o] = Ps[t][9 + o];
      float tp[5];
#pragma unroll
      for (int o = 0; o < 5; ++o) tp[o] = 1.f / (1.f + __expf(-t_[o]));
      float mx = fmaxf(fmaxf(i_[0], i_[1]), fmaxf(i_[2], i_[3]));
      float ex[4], es = 0.f;
#pragma unroll
      for (int o = 0; o < 4; ++o) { ex[o] = __expf(i_[o] - mx); es += ex[o]; }
      float inv_es = 1.f / es;
      float ml[3];
#pragma unroll
      for (int o = 0; o < 3; ++o) {
        float v = mb[o];
#pragma unroll
        for (int j = 0; j < 5; ++j) v += tp[j] * Wm[(128 + j) * 3 + o];
#pragma unroll
        for (int j = 0; j < 4; ++j) v += (ex[j] * inv_es) * Wm[(133 + j) * 3 + o];
        ml[o] = v;
      }
#pragma unroll
      for (int o = 0; o < 5; ++o) out_t[(size_t)row * 5 + o] = t_[o];
#pragma unroll
      for (int o = 0; o < 4; ++o) out_i[(size_t)row * 4 + o] = i_[o];
#pragma unroll
      for (int o = 0; o < 3; ++o) out_m[(size_t)row * 3 + o] = ml[o];
    }
  }
}

// ------------------------------------------------------------------
extern "C" void kernel_launch(void* const* d_in, const int* in_sizes, int n_in,
                              void* d_out, int out_size, void* d_ws, size_t ws_size,
                              hipStream_t stream) {
  const float* x_comment = (const float*)d_in[0];
  const float* x_topic   = (const float*)d_in[1];
  const float* x_claim   = (const float*)d_in[2];
  const float* c1s_Wl = (const float*)d_in[3];
  const float* c1s_bl = (const float*)d_in[4];
  const float* c1s_Wr = (const float*)d_in[5];
  const float* c1a_Wl = (const float*)d_in[6];
  const float* c1a_bl = (const float*)d_in[7];
  const float* c1a_Wr = (const float*)d_in[8];
  const float* c1t_Wl = (const float*)d_in[9];
  const float* c1t_bl = (const float*)d_in[10];
  const float* c1t_Wr = (const float*)d_in[11];
  const float* c2s_Wl = (const float*)d_in[12];
  const float* c2s_bl = (const float*)d_in[13];
  const float* c2s_Wr = (const float*)d_in[14];
  const float* c2a_Wl = (const float*)d_in[15];
  const float* c2a_bl = (const float*)d_in[16];
  const float* c2a_Wr = (const float*)d_in[17];
  const float* c2t_Wl = (const float*)d_in[18];
  const float* c2t_bl = (const float*)d_in[19];
  const float* c2t_Wr = (const float*)d_in[20];
  const float* Wt = (const float*)d_in[21];
  const float* bt = (const float*)d_in[22];
  const float* Wi = (const float*)d_in[23];
  const float* bi = (const float*)d_in[24];
  const float* Wm = (const float*)d_in[25];
  const float* bm = (const float*)d_in[26];
  const int* ei_sim = (const int*)d_in[27];
  const int* ei_ab  = (const int*)d_in[28];
  const int* ei_tg  = (const int*)d_in[29];

  const int E_sim = in_sizes[27] / 2;
  const int E_ab  = in_sizes[28] / 2;
  const int E_tg  = in_sizes[29] / 2;
  const int N_T = in_sizes[1] / 128;
  const int N_CL = in_sizes[2] / 128;

  float* ws = (float*)d_ws;
  unsigned short* h1 = (unsigned short*)ws;                // 100000*128 bf16
  unsigned short* y_s = (unsigned short*)(ws + 12800000);  // 100000*128 bf16 (arena head)
  unsigned short* y_a = (unsigned short*)(ws + 19200000);  // 5000*128 bf16 (arena row 100000)
  unsigned short* y_t = (unsigned short*)(ws + 19520000);  // 20000*128 bf16 (arena row 105000)
  int*   cnt    = (int*)(ws + 20800000);                   // 3*N_C (also fill)
  float* inv    = ws + 21100000;                           // 3*N_C
  int*   base3  = (int*)(ws + 21400000);                   // 3*N_C placement bases
  unsigned int* srcm = (unsigned int*)(ws + 21700016);     // E_sim+E_ab+E_tg merged
  int*   part   = (int*)(ws + 22900016);                   // 128
  float* b1s    = ws + 22900416;
  float* b2s    = ws + 22900544;
  unsigned short* Bt_c1s = (unsigned short*)(ws + 22900672);  // 128x256
  unsigned short* Bt_W1s = Bt_c1s + 32768;                    // 128x256
  unsigned short* Bt_c1a = Bt_W1s + 32768;                    // 128x128
  unsigned short* Bt_c1t = Bt_c1a + 16384;
  unsigned short* Bt_c2s = Bt_c1t + 16384;
  unsigned short* Bt_W2s = Bt_c2s + 16384;
  unsigned short* Bt_c2a = Bt_W2s + 16384;
  unsigned short* Bt_c2t = Bt_c2a + 16384;
  int*   rs_m   = (int*)(ws + 23000000);                   // N_C+1 merged row-ptr
  unsigned short* Wht = (unsigned short*)(ws + 24600000);     // 16x128 bf16
  float* bh     = ws + 24601100;                              // 16

  const int nbS = (N_C + SCAN_CHUNK - 1) / SCAN_CHUNK;
  const int nbC = (N_C + 127) / 128;
  const int nbT = (N_T + 127) / 128;
  const int nbCl = (N_CL + 127) / 128;
  const int nCB = ((E_sim + 2047) >> 11) + ((E_ab + 2047) >> 11) + ((E_tg + 2047) >> 11);
  const int nbGemm1 = 2 * (nbC + nbT + nbCl);
  const size_t lds1 = (3 * 4096 + 2 * 4096) * sizeof(unsigned short);  // 40960
  const size_t lds2 = (3 * 4096 + 2 * 8192) * sizeof(unsigned short);  // 57344

  // ---- degree histogram (fused w/ weight prep) ----
  hipMemsetAsync(cnt, 0, 3 * N_C * sizeof(int), stream);
  prep_count_kernel<<<nCB + 1280, 256, 0, stream>>>(
      c1s_Wl, c1s_Wr, c1a_Wr, c1t_Wr, c1a_Wl, c1t_Wl,
      c2s_Wl, c2s_Wr, c2a_Wr, c2t_Wr, c2a_Wl, c2t_Wl,
      c1s_bl, c1a_bl, c1t_bl, c2s_bl, c2a_bl, c2t_bl,
      Wt, bt, Wi, bi, Wm, bm,
      Bt_c1s, Bt_W1s, Bt_c1a, Bt_c1t, Bt_c2s, Bt_W2s, Bt_c2a, Bt_c2t,
      Wht, b1s, b2s, bh,
      ei_sim, E_sim, ei_ab, E_ab, ei_tg, E_tg, cnt, nCB);

  // ---- merged scan ----
  scan_phaseA<<<dim3(nbS, 1), 256, 0, stream>>>(cnt, part, inv, N_C);
  scan_phaseB<<<dim3(1, 1), 256, 0, stream>>>(part, nbS);
  scan_phaseC<<<dim3(nbS, 1), 256, 0, stream>>>(cnt, part, rs_m, base3, N_C);
  set_totals<<<1, 64, 0, stream>>>(rs_m, E_sim + E_ab + E_tg, N_C);

  // ---------------- layer 1 (fused 3 GEMMs + place3) ----------------
  layer1_kernel<<<nbGemm1 + nCB, 256, lds1, stream>>>(
      x_comment, N_C, Bt_c1s, Bt_W1s, y_s, h1, b1s,
      x_topic, N_T, Bt_c1a, y_a,
      x_claim, N_CL, Bt_c1t, y_t, nbC, nbT, nbCl,
      ei_sim, E_sim, ei_ab, E_ab, ei_tg, E_tg,
      base3, cnt, srcm, N_C, N_C + N_T, N_C);

  gather_kernel<<<(N_C + 3) / 4, 256, 0, stream>>>(
      y_s, rs_m, srcm, inv, h1, N_C);

  // ---------------- layer 2 (fused 3 GEMMs, h in-place bf16) --------
  layer2_kernel<<<nbC + nbT + nbCl, 512, lds2, stream>>>(
      h1, N_C, Bt_c2s, Bt_W2s, y_s, b2s,
      x_topic, N_T, Bt_c2a, y_a,
      x_claim, N_CL, Bt_c2t, y_t, nbC, nbT);

  gather_kernel<<<(N_C + 3) / 4, 256, 0, stream>>>(
      y_s, rs_m, srcm, inv, h1, N_C);

  // ---------------- heads (fully fused) ----------------
  float* out = (float*)d_out;
  heads_kernel<<<(N_C + 63) / 64, 256, 0, stream>>>(
      h1, N_C, Wht, bh, Wm,
      out, out + (size_t)N_C * 5, out + (size_t)N_C * 9);
}